// Round 9
// baseline (4212.747 us; speedup 1.0000x reference)
//
#include <hip/hip_runtime.h>
#include <math.h>

#define HB 8
#define TT 1024
#define NSTATE 16
#define NTT 6
#define NMM 8
#define MM (HB*TT)   /* 8192 rows */
#define EPSV 1e-5f
#define CHUNK 64
#define NCH (TT/CHUNK)   /* 16 */
#define AKS 128          /* attention keys staged per block iter */
#define VST 136          /* kv_split V-transpose LDS stride (halves) */

typedef _Float16 f16x8 __attribute__((ext_vector_type(8)));
typedef _Float16 f16x4 __attribute__((ext_vector_type(4)));
typedef _Float16 f16x2 __attribute__((ext_vector_type(2)));
typedef float f32x4_t __attribute__((ext_vector_type(4)));

static __device__ __forceinline__ void split8(const float4 a, const float4 b,
                                              f16x8& h, f16x8& l)
{
  float x[8] = {a.x, a.y, a.z, a.w, b.x, b.y, b.z, b.w};
#pragma unroll
  for (int i = 0; i < 8; i++) {
    _Float16 hi = (_Float16)x[i];
    h[i] = hi;
    l[i] = (_Float16)(x[i] - (float)hi);
  }
}

// async global->LDS, 16B per lane; LDS dest must be wave-uniform base.
static __device__ __forceinline__ void gload16(const _Float16* g, _Float16* l)
{
  __builtin_amdgcn_global_load_lds(
      (const __attribute__((address_space(1))) unsigned int*)g,
      (__attribute__((address_space(3))) unsigned int*)l, 16, 0, 0);
}

// ---------------------------------------------------------------------------
// Split layout: matrix [rows x K] fp32 -> [K/32 segs][rows][64 halves].
// ---------------------------------------------------------------------------
static __device__ __forceinline__ void store_split(_Float16* __restrict__ dst,
                                                   size_t row, int col, float v)
{
  const int cc = col & 31;
  const size_t o = ((size_t)(col >> 5) * MM + row) * 64
                 + (size_t)(((((cc >> 3) ^ ((int)row & 7)) * 8)) + (cc & 7));
  _Float16 hi = (_Float16)v;
  dst[o] = hi;
  dst[o ^ (size_t)32] = (_Float16)(v - (float)hi);
}

// paired variant: col0 must be even; writes 4B dwords (hi pair, lo pair)
static __device__ __forceinline__ void store_split2(_Float16* __restrict__ dst,
                                                    size_t row, int col0,
                                                    float v0, float v1)
{
  const int cc = col0 & 31;
  const size_t o = ((size_t)(col0 >> 5) * MM + row) * 64
                 + (size_t)(((((cc >> 3) ^ ((int)row & 7)) * 8)) + (cc & 7));
  _Float16 h0 = (_Float16)v0, h1 = (_Float16)v1;
  f16x2 hp = {h0, h1};
  f16x2 lp = {(_Float16)(v0 - (float)h0), (_Float16)(v1 - (float)h1)};
  *(f16x2*)&dst[o] = hp;
  *(f16x2*)&dst[o ^ (size_t)32] = lp;
}

static __device__ __forceinline__ void split_item(
    const float* __restrict__ src, int lda, int rows,
    _Float16* __restrict__ dst, int item)
{
  const int m = item % rows;
  const int seg = item / rows;
  const float* s = src + (size_t)m * lda + seg * 32;
  _Float16* d = dst + (size_t)item * 64;
  const int swz = m & 7;
#pragma unroll
  for (int g = 0; g < 4; g++) {
    float4 x0 = *(const float4*)&s[g * 8];
    float4 x1 = *(const float4*)&s[g * 8 + 4];
    f16x8 h, l;
    split8(x0, x1, h, l);
    const int u = (g ^ swz) * 8;
    *(f16x8*)&d[u] = h;
    *(f16x8*)&d[u ^ 32] = l;
  }
}

__global__ __launch_bounds__(256) void split_k(
    const float* __restrict__ src, int lda, int rows,
    _Float16* __restrict__ dst)
{
  split_item(src, lda, rows, dst, blockIdx.x * 256 + threadIdx.x);
}

// fused 3-region split (per mamba layer: inproj / xproj / dtw weights)
__global__ __launch_bounds__(256) void split3_k(
    const float* __restrict__ s0, int lda0, int rows0, _Float16* __restrict__ d0, int nb0,
    const float* __restrict__ s1, int lda1, int rows1, _Float16* __restrict__ d1, int nb1,
    const float* __restrict__ s2, int lda2, int rows2, _Float16* __restrict__ d2)
{
  const int bid = blockIdx.x;
  if (bid < nb0) {
    split_item(s0, lda0, rows0, d0, bid * 256 + threadIdx.x);
  } else if (bid < nb0 + nb1) {
    split_item(s1, lda1, rows1, d1, (bid - nb0) * 256 + threadIdx.x);
  } else {
    split_item(s2, lda2, rows2, d2, (bid - nb0 - nb1) * 256 + threadIdx.x);
  }
}

// fused 6-region split (one-time transformer weights + emb; c* are cum blocks)
__global__ __launch_bounds__(256) void split6_k(
    const float* __restrict__ s0, int lda0, int rows0, _Float16* __restrict__ d0, int c0,
    const float* __restrict__ s1, int lda1, int rows1, _Float16* __restrict__ d1, int c1,
    const float* __restrict__ s2, int lda2, int rows2, _Float16* __restrict__ d2, int c2,
    const float* __restrict__ s3, int lda3, int rows3, _Float16* __restrict__ d3, int c3,
    const float* __restrict__ s4, int lda4, int rows4, _Float16* __restrict__ d4, int c4,
    const float* __restrict__ s5, int lda5, int rows5, _Float16* __restrict__ d5)
{
  const int bid = blockIdx.x;
  if (bid < c0)      split_item(s0, lda0, rows0, d0, bid * 256 + threadIdx.x);
  else if (bid < c1) split_item(s1, lda1, rows1, d1, (bid - c0) * 256 + threadIdx.x);
  else if (bid < c2) split_item(s2, lda2, rows2, d2, (bid - c1) * 256 + threadIdx.x);
  else if (bid < c3) split_item(s3, lda3, rows3, d3, (bid - c2) * 256 + threadIdx.x);
  else if (bid < c4) split_item(s4, lda4, rows4, d4, (bid - c3) * 256 + threadIdx.x);
  else               split_item(s5, lda5, rows5, d5, (bid - c4) * 256 + threadIdx.x);
}

// ---------------------------------------------------------------------------
// K/V split producer for attention (unchanged).
// ---------------------------------------------------------------------------
__global__ __launch_bounds__(256) void kv_split_k(
    const float* __restrict__ qkv,
    _Float16* __restrict__ Ks, _Float16* __restrict__ Vs)
{
  __shared__ _Float16 Vthi[16 * VST], Vtlo[16 * VST];
  const int tid = threadIdx.x;
  const int bh = blockIdx.y;
  const int b = bh >> 3;
  const int h = bh & 7;
  const int kb0 = blockIdx.x * 128;

  const int kl = tid >> 1;
  const int half = tid & 1;
  const int key = kb0 + kl;
  const float* kp = qkv + (size_t)(b * TT + key) * 384 + 128 + h * 16 + half * 8;

  {
    float4 k0 = *(const float4*)&kp[0];
    float4 k1 = *(const float4*)&kp[4];
    f16x8 hh, ll;
    split8(k0, k1, hh, ll);
    const int p = (half + (key >> 1)) & 3;
    _Float16* kb = Ks + (((size_t)bh << 10) + key) * 32;
    *(f16x8*)&kb[p * 8] = hh;
    *(f16x8*)&kb[(p ^ 2) * 8] = ll;
  }
  {
    float4 v0 = *(const float4*)&kp[128];
    float4 v1 = *(const float4*)&kp[132];
    float xv[8] = {v0.x, v0.y, v0.z, v0.w, v1.x, v1.y, v1.z, v1.w};
#pragma unroll
    for (int j = 0; j < 8; j++) {
      const int d = half * 8 + j;
      _Float16 hi = (_Float16)xv[j];
      Vthi[d * VST + kl] = hi;
      Vtlo[d * VST + kl] = (_Float16)(xv[j] - (float)hi);
    }
  }
  __syncthreads();
  {
    const int d = tid >> 4;
    const int kg = tid & 15;
    f16x8 hh = *(const f16x8*)&Vthi[d * VST + kg * 8];
    f16x8 ll = *(const f16x8*)&Vtlo[d * VST + kg * 8];
    _Float16* vb = Vs + ((size_t)bh * 32 + d) * 1024 + kb0 + ((kg ^ d) * 8);
    *(f16x8*)&vb[0] = hh;
    *(f16x8*)&vb[16 * 1024] = ll;
  }
}

// ---------------------------------------------------------------------------
// fp16x3 split-precision MFMA GEMM, XCD-aware flattened grid (unchanged).
// ---------------------------------------------------------------------------
template<int TN>
__global__ __launch_bounds__(256, 4) void gemm_ps_t(
    const _Float16* __restrict__ Ap, int astr,
    const _Float16* __restrict__ Wp, int wstr,
    const float* __restrict__ bias,
    float* __restrict__ C,
    float* __restrict__ P,
    _Float16* __restrict__ Cs,
    int N, int K, int S, int act)
{
  __shared__ __align__(16) _Float16 As[128 * 64];
  __shared__ __align__(16) _Float16 Bs[TN * 64];
  const int tid = threadIdx.x;
  const int lane = tid & 63;
  const int w = tid >> 6;
  const int quad = lane >> 4;
  const int l16 = lane & 15;

  const int gx = N / TN;
  const int bid = blockIdx.x;
  const int xcd = bid & 7;
  const int i = bid >> 3;
  const int iq = i / gx;
  const int by = xcd * 8 + iq;
  const int bx = i - iq * gx;

  const int m0 = by * 128;
  const int n0 = bx * TN;
  const int z = blockIdx.z;
  const int nseg = K / 32;
  const int segb = z * (nseg / S);
  const int sege = segb + nseg / S;

  constexpr int MI = (TN == 128) ? 4 : 2;
  const int w0 = (TN == 128) ? (w & 1) : w;
  const int w1 = (TN == 128) ? (w >> 1) : 0;
  const int rowbase = (TN == 128) ? w0 * 64 : w0 * 32;

  f32x4_t acc[MI][4];
#pragma unroll
  for (int i2 = 0; i2 < MI; i2++)
#pragma unroll
    for (int j = 0; j < 4; j++)
#pragma unroll
      for (int r = 0; r < 4; r++) acc[i2][j][r] = 0.f;

  const int sw8 = (quad ^ (l16 & 7)) * 8;                 // hi unit offset
  const int abase = (rowbase + l16) * 64 + sw8;
  const int bbase = (w1 * 64 + l16) * 64 + sw8;
  const int wave64 = tid & 192;                            // wave*64

  for (int seg = segb; seg < sege; seg++) {
    const _Float16* At = Ap + ((size_t)seg * astr + m0) * 64;
    const _Float16* Bt = Wp + ((size_t)seg * wstr + n0) * 64;
    __syncthreads();
#pragma unroll
    for (int j = 0; j < 4; j++)
      gload16(At + (size_t)(j * 256 + tid) * 8, &As[(j * 256 + wave64) * 8]);
#pragma unroll
    for (int j = 0; j < TN / 32; j++)
      gload16(Bt + (size_t)(j * 256 + tid) * 8, &Bs[(j * 256 + wave64) * 8]);
    __syncthreads();

    f16x8 bh[4], bl[4];
#pragma unroll
    for (int ni = 0; ni < 4; ni++) {
      bh[ni] = *(const f16x8*)&Bs[bbase + ni * 1024];
      bl[ni] = *(const f16x8*)&Bs[(bbase ^ 32) + ni * 1024];
    }
#pragma unroll
    for (int mi = 0; mi < MI; mi++) {
      f16x8 ah = *(const f16x8*)&As[abase + mi * 1024];
      f16x8 al = *(const f16x8*)&As[(abase ^ 32) + mi * 1024];
#pragma unroll
      for (int ni = 0; ni < 4; ni++) {
        acc[mi][ni] = __builtin_amdgcn_mfma_f32_16x16x32_f16(ah, bh[ni], acc[mi][ni], 0, 0, 0);
        acc[mi][ni] = __builtin_amdgcn_mfma_f32_16x16x32_f16(ah, bl[ni], acc[mi][ni], 0, 0, 0);
        acc[mi][ni] = __builtin_amdgcn_mfma_f32_16x16x32_f16(al, bh[ni], acc[mi][ni], 0, 0, 0);
      }
    }
  }

  float* dst = (S == 1) ? C : (P + (size_t)z * MM * N);
#pragma unroll
  for (int ni = 0; ni < 4; ni++) {
    const int n = n0 + w1 * 64 + ni * 16 + l16;
    const float bv = (S == 1 && bias) ? bias[n] : 0.f;
#pragma unroll
    for (int mi = 0; mi < MI; mi++) {
      const int mbase = m0 + rowbase + mi * 16 + quad * 4;
#pragma unroll
      for (int r = 0; r < 4; r++) {
        float v = acc[mi][ni][r] + bv;
        if (S == 1) {
          if (act == 1) v = fmaxf(v, 0.f);
          else if (act == 2) v = fmaxf(v, 0.f) + log1pf(__expf(-fabsf(v)));
        }
        const int row = mbase + r;
        if (S == 1 && Cs) {
          store_split(Cs, (size_t)row, n, v);
        } else {
          dst[(size_t)row * N + n] = v;
        }
      }
    }
  }
}

// ---------------------------------------------------------------------------
// Split-K reduce: C(or split Cs) = act( sum_z P[z] + bias ).
// ---------------------------------------------------------------------------
__global__ __launch_bounds__(256) void reduce_k(
    const float* __restrict__ P, const float* __restrict__ bias,
    float* __restrict__ C, _Float16* __restrict__ Cs,
    _Float16* __restrict__ dta,
    int nmask, int nshift, int S, int act, int stride4)
{
  const int idx = blockIdx.x * 256 + threadIdx.x;
  float4 a = *(const float4*)&P[(size_t)idx * 4];
  for (int z = 1; z < S; z++) {
    float4 p = *(const float4*)&P[(size_t)(idx + (size_t)z * stride4) * 4];
    a.x += p.x; a.y += p.y; a.z += p.z; a.w += p.w;
  }
  if (bias) {
    float4 bv = *(const float4*)&bias[(idx * 4) & nmask];
    a.x += bv.x; a.y += bv.y; a.z += bv.z; a.w += bv.w;
  }
  if (act == 1) {
    a.x = fmaxf(a.x, 0.f); a.y = fmaxf(a.y, 0.f);
    a.z = fmaxf(a.z, 0.f); a.w = fmaxf(a.w, 0.f);
  } else if (act == 2) {
    a.x = fmaxf(a.x, 0.f) + log1pf(__expf(-fabsf(a.x)));
    a.y = fmaxf(a.y, 0.f) + log1pf(__expf(-fabsf(a.y)));
    a.z = fmaxf(a.z, 0.f) + log1pf(__expf(-fabsf(a.z)));
    a.w = fmaxf(a.w, 0.f) + log1pf(__expf(-fabsf(a.w)));
  }
  const int c0 = (idx * 4) & nmask;
  const size_t row = (size_t)(idx * 4) >> nshift;
  if (Cs) {
    store_split2(Cs, row, c0,     a.x, a.y);
    store_split2(Cs, row, c0 + 2, a.z, a.w);
  } else {
    *(float4*)&C[(size_t)idx * 4] = a;
  }
  if (dta && c0 < 32) {
    store_split2(dta, row, c0,     a.x, a.y);
    store_split2(dta, row, c0 + 2, a.z, a.w);
  }
}

// ---------------------------------------------------------------------------
// MFMA flash attention, swapped-operand QK: S^T = mfma(K, Q) puts
// S[key=quad*4+r][query=l16] in registers; the PV A-frag is gathered with 8
// __shfl (no LDS P roundtrip, no lgkmcnt(0) serializers, no bank conflicts).
// Denominator: per-key-mod-16 chains + in-register tree + shfl_xor(16) —
// replicates the old butterfly node structure exactly (bit-identical).
// 64 queries/block, grid (TT/64, HB*8) -> 4 blocks/CU.
// ---------------------------------------------------------------------------
__global__ __launch_bounds__(256, 4) void attn_mfma_k(
    const float* __restrict__ qkv,
    const _Float16* __restrict__ Kg,
    const _Float16* __restrict__ Vg,
    _Float16* __restrict__ os)
{
  __shared__ __align__(16) _Float16 Klds[AKS * 32];     // [key][32]
  __shared__ __align__(16) _Float16 Vlds[32 * AKS];     // [plane*16+d][128]

  const int tid = threadIdx.x;
  const int lane = tid & 63;
  const int wv = tid >> 6;
  const int quad = lane >> 4;
  const int l16 = lane & 15;
  const int qh = quad & 1;
  const int bh = blockIdx.y;
  const int b = bh >> 3;
  const int h = bh & 7;
  const int qb0 = blockIdx.x * 64;
  const int wave64 = tid & 192;

  // Q frag (B-operand): n=query=l16, k-slots quad*8+j = dims qh*8+j, hi/lo
  f16x8 qa;
  {
    const int qrow = qb0 + wv * 16 + l16;
    const float* qp = qkv + (size_t)(b * TT + qrow) * 384 + h * 16 + qh * 8;
    float4 x0 = *(const float4*)&qp[0];
    float4 x1 = *(const float4*)&qp[4];
    float xv[8] = {x0.x, x0.y, x0.z, x0.w, x1.x, x1.y, x1.z, x1.w};
#pragma unroll
    for (int j = 0; j < 8; j++) {
      float q = xv[j] * 0.25f;
      _Float16 hi = (_Float16)q;
      _Float16 lo = (_Float16)(q - (float)hi);
      qa[j] = (quad < 2) ? hi : lo;
    }
  }

  f32x4_t oacc;
  float dch[8];   // serial chains per key-mod-16 (keys 8*qh+j), query=l16
#pragma unroll
  for (int r = 0; r < 4; r++) oacc[r] = 0.f;
#pragma unroll
  for (int j = 0; j < 8; j++) dch[j] = 0.f;

  const _Float16* Kb = Kg + (((size_t)bh) << 10) * 32;
  const _Float16* Vb = Vg + ((size_t)bh * 32) * 1024;

  for (int ks = 0; ks < TT; ks += AKS) {
    __syncthreads();
    // stage K (8KB) + V (8KB) via global_load_lds
    {
      const _Float16* Kt = Kb + (size_t)ks * 32;
#pragma unroll
      for (int it = 0; it < 2; it++) {
        const int cb = it * 256 + tid;
        gload16(Kt + (size_t)cb * 8, &Klds[(it * 256 + wave64) * 8]);
      }
#pragma unroll
      for (int it = 0; it < 2; it++) {
        const int cb = it * 256 + tid;
        const int rowv = cb >> 4, co = cb & 15;
        gload16(Vb + (size_t)rowv * 1024 + ks + co * 8,
                &Vlds[(it * 256 + wave64) * 8]);
      }
    }
    __syncthreads();

    for (int kt = 0; kt < AKS; kt += 16) {
      const int key = kt + l16;
      const int ph = (qh + (key >> 1)) & 3;
      f16x8 kfh = *(const f16x8*)&Klds[key * 32 + ph * 8];
      f16x8 kfl = *(const f16x8*)&Klds[key * 32 + (ph ^ 2) * 8];
      const int vko = (kt + qh * 8) ^ (l16 * 8);
      f16x8 vfh = *(const f16x8*)&Vlds[l16 * 128 + vko];
      f16x8 vfl = *(const f16x8*)&Vlds[(16 + l16) * 128 + vko];

      // swapped QK: A=K (m=key=l16), B=Q (n=query=l16); same products per
      // k-slot as the unswapped form -> bit-identical S.
      f32x4_t s;
#pragma unroll
      for (int r = 0; r < 4; r++) s[r] = 0.f;
      __builtin_amdgcn_s_setprio(1);
      s = __builtin_amdgcn_mfma_f32_16x16x32_f16(kfh, qa, s, 0, 0, 0);
      s = __builtin_amdgcn_mfma_f32_16x16x32_f16(kfl, qa, s, 0, 0, 0);
      __builtin_amdgcn_s_setprio(0);

      float p[4];
#pragma unroll
      for (int r = 0; r < 4; r++) p[r] = __expf(s[r]);   // P[kt+4*quad+r][l16]

      // gather PV A-frag: lane needs P[query=l16][key kt+8*qh+j]
      f16x8 pa;
#pragma unroll
      for (int j = 0; j < 8; j++) {
        const float pv = __shfl(p[j & 3], ((qh * 2 + (j >> 2)) << 4) + l16);
        dch[j] += pv;
        _Float16 hi = (_Float16)pv;
        _Float16 lo = (_Float16)(pv - (float)hi);
        pa[j] = (quad < 2) ? hi : lo;
      }

      __builtin_amdgcn_s_setprio(1);
      oacc = __builtin_amdgcn_mfma_f32_16x16x32_f16(pa, vfh, oacc, 0, 0, 0);
      oacc = __builtin_amdgcn_mfma_f32_16x16x32_f16(pa, vfl, oacc, 0, 0, 0);
      __builtin_amdgcn_s_setprio(0);
    }
  }

  // denominator: tree over key bits 1,2,4 in-register, bit 8 across qh.
  const float e0 = dch[0] + dch[1], e1 = dch[2] + dch[3];
  const float e2 = dch[4] + dch[5], e3 = dch[6] + dch[7];
  const float g = (e0 + e1) + (e2 + e3);
  const float lv = g + __shfl_xor(g, 16);   // denom(query = l16), all lanes

#pragma unroll
  for (int r = 0; r < 4; r++) {
    const float dq = __shfl(lv, quad * 4 + r);   // denom of query quad*4+r
    const float inv = 1.f / dq;
    const int qrow = qb0 + wv * 16 + quad * 4 + r;
    const size_t m = (size_t)(b * TT + qrow);
    store_split(os, m, h * 16 + l16, oacc[r] * inv);
  }
}

// ---------------------------------------------------------------------------
// out = LN(a + bvec) * w + bb  (fp32 out + fused split out)
// ---------------------------------------------------------------------------
__global__ __launch_bounds__(256) void add_ln_k(
    const float* __restrict__ a, const float* __restrict__ bvec,
    const float* __restrict__ w, const float* __restrict__ bb,
    float* __restrict__ out, _Float16* __restrict__ outs)
{
  const int tid = threadIdx.x;
  const int wave = tid >> 6, lane = tid & 63;
  const size_t row = (size_t)blockIdx.x * 4 + wave;
  const float* pa = a + row * 128;
  const float* pb = bvec + row * 128;
  float v0 = pa[lane] + pb[lane];
  float v1 = pa[lane + 64] + pb[lane + 64];
  float s1 = v0 + v1, s2 = v0 * v0 + v1 * v1;
#pragma unroll
  for (int off = 32; off; off >>= 1) {
    s1 += __shfl_down(s1, off);
    s2 += __shfl_down(s2, off);
  }
  s1 = __shfl(s1, 0); s2 = __shfl(s2, 0);
  const float mean = s1 * (1.f / 128.f);
  const float var = s2 * (1.f / 128.f) - mean * mean;
  const float rs = rsqrtf(var + EPSV);
  const float o0 = (v0 - mean) * rs * w[lane] + bb[lane];
  const float o1 = (v1 - mean) * rs * w[lane + 64] + bb[lane + 64];
  out[row * 128 + lane] = o0;
  out[row * 128 + lane + 64] = o1;
  store_split(outs, row, lane, o0);
  store_split(outs, row, lane + 64, o1);
}

// ---------------------------------------------------------------------------
// Depthwise causal conv (DC=4) + SiLU; 4 t-steps x 2 channels per thread.
// ---------------------------------------------------------------------------
__global__ __launch_bounds__(256) void conv_silu_k(
    const float* __restrict__ xz, const float* __restrict__ cw,
    const float* __restrict__ cb, float* __restrict__ out,
    _Float16* __restrict__ outs)
{
  const int idx = blockIdx.x * 256 + threadIdx.x;   // over (MM/4)*512
  const int di = (idx & 511) * 2;
  const int tg = idx >> 9;
  const int m0 = tg * 4;
  const int t0 = m0 & (TT - 1);

  float wa[4], wb[4];
#pragma unroll
  for (int k = 0; k < 4; k++) {
    wa[k] = cw[di * 4 + k];
    wb[k] = cw[di * 4 + 4 + k];
  }
  const float b0 = cb[di], b1 = cb[di + 1];

  float2 xr[7];
#pragma unroll
  for (int j = 0; j < 7; j++) {
    if (t0 + j - 3 >= 0) {
      xr[j] = *(const float2*)&xz[(size_t)(m0 + j - 3) * 2048 + di];
    } else {
      xr[j].x = 0.f; xr[j].y = 0.f;
    }
  }

#pragma unroll
  for (int j = 0; j < 4; j++) {
    float a0 = b0, a1 = b1;
#pragma unroll
    for (int k = 0; k < 4; k++) {
      a0 += xr[j + k].x * wa[k];
      a1 += xr[j + k].y * wb[k];
    }
    const float y0 = a0 / (1.f + __expf(-a0));
    const float y1 = a1 / (1.f + __expf(-a1));
    float2 yo = {y0, y1};
    const size_t m = (size_t)(m0 + j);
    *(float2*)&out[m * 1024 + di] = yo;
    store_split2(outs, m, di, y0, y1);
  }
}

// ---------------------------------------------------------------------------
// Chunked selective scan, phase A: local scan, emit P=prod(dA), S=local h.
// ---------------------------------------------------------------------------
__global__ __launch_bounds__(64) void scan_partial_k(
    const float* __restrict__ dt,
    const float* __restrict__ dbc,
    const float* __restrict__ xi,
    const float* __restrict__ Alog,
    float* __restrict__ Pb, float* __restrict__ Sb)
{
  const int slice = blockIdx.x & 15;
  const int c = blockIdx.x >> 4;
  const int b = blockIdx.y;
  const int di = slice * 64 + threadIdx.x;

  float A[NSTATE];
#pragma unroll
  for (int n = 0; n < NSTATE; n++) A[n] = -__expf(Alog[di * NSTATE + n]);
  float h[NSTATE], P[NSTATE];
#pragma unroll
  for (int n = 0; n < NSTATE; n++) { h[n] = 0.f; P[n] = 1.f; }

  const size_t m0 = (size_t)b * TT + (size_t)c * CHUNK;
  for (int t = 0; t < CHUNK; t++) {
    const size_t m = m0 + t;
    const float dtv = dt[m * 1024 + di];
    const float xv  = xi[m * 1024 + di];
    const float dtx = dtv * xv;
#pragma unroll
    for (int n = 0; n < NSTATE; n++) {
      const float Bv = dbc[m * 64 + 32 + n];
      const float dA = __expf(dtv * A[n]);
      h[n] = h[n] * dA + dtx * Bv;
      P[n] *= dA;
    }
  }
  const size_t base = (((size_t)b * NCH + c) * NSTATE) * 1024 + di;
#pragma unroll
  for (int n = 0; n < NSTATE; n++) {
    Pb[base + (size_t)n * 1024] = P[n];
    Sb[base + (size_t)n * 1024] = h[n];
  }
}

// ---------------------------------------------------------------------------
// Phase B: sequential chunk fix-up, one thread per (b, di, n).
// ---------------------------------------------------------------------------
__global__ __launch_bounds__(256) void scan_fix_k(
    float* __restrict__ Pb, const float* __restrict__ Sb)
{
  const int idx = blockIdx.x * 256 + threadIdx.x;   // over HB*16*1024
  const int di = idx & 1023;
  const int n  = (idx >> 10) & 15;
  const int b  = idx >> 14;
  float h = 0.f;
  for (int c = 0; c < NCH; c++) {
    const size_t base = (((size_t)b * NCH + c) * NSTATE + n) * 1024 + di;
    const float P = Pb[base];
    const float S = Sb[base];
    Pb[base] = h;
    h = P * h + S;
  }
}

// ---------------------------------------------------------------------------
// Phase C: re-run each chunk from h_in; y = dot(h,C) + D*x; *= silu(z).
// ---------------------------------------------------------------------------
__global__ __launch_bounds__(64) void scan_final_k(
    const float* __restrict__ dt,
    const float* __restrict__ dbc,
    const float* __restrict__ xi,
    const float* __restrict__ xz,
    const float* __restrict__ Alog,
    const float* __restrict__ Dp,
    const float* __restrict__ Hin,
    _Float16* __restrict__ Y)
{
  const int slice = blockIdx.x & 15;
  const int c = blockIdx.x >> 4;
  const int b = blockIdx.y;
  const int di = slice * 64 + threadIdx.x;

  float A[NSTATE];
#pragma unroll
  for (int n = 0; n < NSTATE; n++) A[n] = -__expf(Alog[di * NSTATE + n]);
  const float Dv = Dp[di];
  float h[NSTATE];
  const size_t hbase = (((size_t)b * NCH + c) * NSTATE) * 1024 + di;
#pragma unroll
  for (int n = 0; n < NSTATE; n++) h[n] = Hin[hbase + (size_t)n * 1024];

  const size_t m0 = (size_t)b * TT + (size_t)c * CHUNK;
  for (int t = 0; t < CHUNK; t++) {
    const size_t m = m0 + t;
    const float dtv = dt[m * 1024 + di];
    const float xv  = xi[m * 1024 + di];
    const float zv  = xz[m * 2048 + 1024 + di];
    const float dtx = dtv * xv;
    float y = 0.f;
#pragma unroll
    for (int n = 0; n < NSTATE; n++) {
      const float Bv = dbc[m * 64 + 32 + n];
      const float Cv = dbc[m * 64 + 48 + n];
      const float dA = __expf(dtv * A[n]);
      h[n] = h[n] * dA + dtx * Bv;
      y += h[n] * Cv;
    }
    y += Dv * xv;
    y *= zv / (1.f + __expf(-zv));
    store_split(Y, m, di, y);
  }
}

// ---------------------------------------------------------------------------
extern "C" void kernel_launch(void* const* d_in, const int* in_sizes, int n_in,
                              void* d_out, int out_size, void* d_ws, size_t ws_size,
                              hipStream_t stream)
{
  (void)in_sizes; (void)n_in; (void)out_size; (void)ws_size;
  const float* emb      = (const float*)d_in[0];
  const float* t_wqkv   = (const float*)d_in[1];
  const float* t_bqkv   = (const float*)d_in[2];
  const float* t_wo     = (const float*)d_in[3];
  const float* t_bo     = (const float*)d_in[4];
  const float* t_ln1w   = (const float*)d_in[5];
  const float* t_ln1b   = (const float*)d_in[6];
  const float* t_w1     = (const float*)d_in[7];
  const float* t_b1     = (const float*)d_in[8];
  const float* t_w2     = (const float*)d_in[9];
  const float* t_b2     = (const float*)d_in[10];
  const float* t_ln2w   = (const float*)d_in[11];
  const float* t_ln2b   = (const float*)d_in[12];
  const float* w_in     = (const float*)d_in[13];
  const float* b_in     = (const float*)d_in[14];
  const float* m_inproj = (const float*)d_in[15];
  const float* m_convw  = (const float*)d_in[16];
  const float* m_convb  = (const float*)d_in[17];
  const float* m_xproj  = (const float*)d_in[18];
  const float* m_dtw    = (const float*)d_in[19];
  const float* m_dtb    = (const float*)d_in[20];
  const float* m_Alog   = (const float*)d_in[21];
  const float* m_D      = (const float*)d_in[22];
  const float* m_outproj= (const float*)d_in[23];
  const float* w_out    = (const float*)d_in[24];
  const float* b_out    = (const float*)d_in[25];

  // Workspace: EXACTLY the round-0 footprint (MM*6208 floats, 203.4 MB).
  float* ws = (float*)d_ws;
  float* R1 = ws;                         // MM*512   x fp32 | mamba xos/xcs
  float* R2 = ws + (size_t)MM * 512;      // MM*512   wo partials + KV split | mamba xcs/xos
  float* R3 = ws + (size_t)MM * 1024;     // MM*2048  qkv | w1 split | xz | outproj partials
  float* R4 = ws + (size_t)MM * 3072;     // MM*1024  transformer weight splits | xi fp32
  float* R5 = ws + (size_t)MM * 4096;     // MM*1024  wo/w2 out fp32 | dt fp32
  float* R6 = ws + (size_t)MM * 5120;     // MM*1024  ASP1 + w2 partials | xi-split/DTA/Y-split
  float* R7 = ws + (size_t)MM * 6144;     // MM*64    dbc

  // transformer weight splits in R4
  _Float16* TWQKV = (_Float16*)R4;                    // 6*384  x 128
  _Float16* TWO   = TWQKV + (size_t)294912 * 2;       // 6*128  x 128
  _Float16* TW1   = TWO   + (size_t)98304 * 2;        // 6*2048 x 128
  _Float16* TW2   = TW1   + (size_t)1572864 * 2;      // 6*128  x 2048
  _Float16* TWIN  = TW2   + (size_t)1572864 * 2;      // 512    x 128  (ends at MM*440)

  _Float16* ASP1 = (_Float16*)R6;                     // M x 128 split
  _Float16* XIS  = (_Float16*)R6;                     // M x 1024 split (mamba)
  _Float16* DTA  = (_Float16*)R6;                     // M x 32 split
  _Float16* YSP  = (_Float16*)R6;                     // M x 1024 split (scan out)

  // attention K/V split buffers in R2 tail (wo partials use R2[0:MM*256))
  _Float16* KG = (_Float16*)(R2 + (size_t)MM * 256);  // 64*1024*32 halves (4MB)
  _Float16* VG = (_Float16*)(R2 + (size_t)MM * 320);  // 64*32*1024 halves (4MB)

  dim3 blk(256);
  auto split = [&](const float* src, int lda, int rows, int K, _Float16* dst) {
    hipLaunchKernelGGL(split_k, dim3(rows * (K / 32) / 256), blk, 0, stream,
                       src, lda, rows, dst);
  };
  auto gemm = [&](const _Float16* Ap, const _Float16* Wp, int wstr,
                  const float* bias, float* C, int N, int K, int act,
                  int S, float* P, _Float16* Cs, _Float16* dta, bool tn64) {
    dim3 g((N / (tn64 ? 64 : 128)) * (MM / 128), 1, S);
    if (tn64)
      hipLaunchKernelGGL(gemm_ps_t<64>, g, blk, 0, stream,
                         Ap, MM, Wp, wstr, bias, C, P, Cs, N, K, S, act);
    else
      hipLaunchKernelGGL(gemm_ps_t<128>, g, blk, 0, stream,
                         Ap, MM, Wp, wstr, bias, C, P, Cs, N, K, S, act);
    if (S > 1) {
      int stride4 = (int)((size_t)MM * N / 4);
      hipLaunchKernelGGL(reduce_k, dim3(stride4 / 256), blk, 0, stream,
                         P, bias, C, Cs, dta, N - 1, __builtin_ctz(N), S, act,
                         stride4);
    }
  };

  // ---- one-time splits, single launch (wqkv|wo|w1|w2|w_in|emb) ----
  hipLaunchKernelGGL(split6_k, dim3(568), blk, 0, stream,
      t_wqkv, 128,  2304, TWQKV,  36,
      t_wo,   128,   768, TWO,    48,
      t_w1,   128, 12288, TW1,   240,
      t_w2,  2048,   768, TW2,   432,
      w_in,   128,   512, TWIN,  440,
      emb,    128,    MM, ASP1);

  // ---- transformer stack ----
  const float* x = emb;
  for (int l = 0; l < NTT; l++) {
    // qkv: N=384 K=128, plain fp32 out -> R3
    gemm(ASP1, TWQKV + (size_t)l * 384 * 64, 2304, t_bqkv + l * 384,
         R3, 384, 128, 0, 1, nullptr, nullptr, nullptr, false);
    // K/V -> split buffers (coalesced)
    hipLaunchKernelGGL(kv_split_k, dim3(8, HB * 8), blk, 0, stream,
                       R3, KG, VG);
    // attention -> split ASP1 (wo's A)
    hipLaunchKernelGGL(attn_mfma_k, dim3(TT / 64, HB * 8), blk, 0, stream,
                       R3, KG, VG, ASP1);
    // wo: N=128 K=128, S=2, partials in R2 head
    gemm(ASP1, TWO + (size_t)l * 128 * 64, 768, t_bo + l * 128,
         R5, 128, 128, 0, 2, R2, nullptr, nullptr, true);
    hipLaunchKernelGGL(add_ln_k, dim3(MM / 4), blk, 0, stream,
                       x, R5, t_ln1w + l * 128, t_ln1b + l * 128, R1, ASP1);
    // w1: N=2048 K=128, relu, split-only output overlaid in R3 (w2's A)
    gemm(ASP1, TW1 + (size_t)l * 2048 * 64, 12288, t_b1 + l * 2048,
         R3, 2048, 128, 1, 1, nullptr, (_Float16*)R3, nullptr, false);
    // w2: N=128 K=2048, S=8, partials fill R6 (ASP1 dead here)
    gemm((_Float16*)R3, TW2 + (size_t)l * 128 * 64, 768, t_b2 + l * 128,
         R5, 128, 2048, 0, 8, R6, nullptr, nullptr, false);
    hipLaunchKernelGGL(add_ln_k, dim3(MM / 4), blk, 0, stream,
                       R1, R5, t_ln2w + l * 128, t_ln2b + l * 128, R1, ASP1);
    x = R1;
  }

  // w_in: N=512 K=128, split-only output -> R2 (mamba x)
  gemm(ASP1, TWIN, 512, b_in, R2, 512, 128, 0, 1, nullptr, (_Float16*)R2,
       nullptr, false);

  float* xcs = R2;
  float* xos = R1;
  for (int l = 0; l < NMM; l++) {
    // per-layer mamba weight splits into dead slivers of xos
    _Float16* WIs = (_Float16*)(xos + (size_t)MM * 256);
    _Float16* WXs = (_Float16*)(xos + (size_t)MM * 384);
    _Float16* WDs = (_Float16*)(xos + (size_t)MM * 392);
    _Float16* WOs = (_Float16*)(xos + (size_t)MM * 256);  // after scan_fix
    hipLaunchKernelGGL(split3_k, dim3(140), blk, 0, stream,
        m_inproj + (size_t)l * 2048 * 512, 512, 2048, WIs, 128,
        m_xproj  + (size_t)l * 64 * 1024, 1024,   64, WXs,   8,
        m_dtw    + (size_t)l * 1024 * 32,   32, 1024, WDs);

    // inproj: N=2048 K=512, fp32 out (conv + z) -> R3
    gemm((_Float16*)xcs, WIs, 2048, nullptr,
         R3, 2048, 512, 0, 1, nullptr, nullptr, nullptr, false);
    hipLaunchKernelGGL(conv_silu_k, dim3(MM / 2), blk, 0, stream,
                       R3, m_convw + (size_t)l * 1024 * 4, m_convb + l * 1024,
                       R4, XIS);
    // xproj: N=64 K=1024, S=4, partials xos[0:256); reduce also emits DTA
    gemm(XIS, WXs, 64, nullptr,
         R7, 64, 1024, 0, 4, xos, nullptr, DTA, true);
    // dtw: N=1024 K=32, softplus -> R5
    gemm(DTA, WDs, 1024, m_dtb + l * 1024,
         R5, 1024, 32, 2, 1, nullptr, nullptr, nullptr, false);

    float* Pb = xos;
    float* Sb = xos + (size_t)MM * 256;
    hipLaunchKernelGGL(scan_partial_k, dim3(16 * NCH, HB), dim3(64), 0, stream,
                       R5, R7, R4, m_Alog + (size_t)l * 1024 * 16, Pb, Sb);
    hipLaunchKernelGGL(scan_fix_k, dim3(HB * NSTATE * 1024 / 256), blk, 0,
                       stream, Pb, Sb);
    // outproj weight split now (Sb dead, Pb still live for scan_final)
    split(m_outproj + (size_t)l * 512 * 1024, 1024, 512, 1024, WOs);
    hipLaunchKernelGGL(scan_final_k, dim3(16 * NCH, HB), dim3(64), 0, stream,
                       R5, R7, R4, R3,
                       m_Alog + (size_t)l * 1024 * 16, m_D + l * 1024, Pb, YSP);

    // outproj: N=512 K=1024, S=2, partials R3 (xz dead), split out -> xos
    gemm(YSP, WOs, 512, nullptr,
         R5, 512, 1024, 0, 2, R3, (_Float16*)xos, nullptr, false);
    float* ts = xcs; xcs = xos; xos = ts;
  }

  // w_out: N=128 K=512, S=4, partials in R6 (dead); weight split in xos (dead)
  _Float16* WOUTs = (_Float16*)xos;
  split(w_out, 512, 128, 512, WOUTs);
  gemm((_Float16*)xcs, WOUTs, 128, b_out,
       (float*)d_out, 128, 512, 0, 4, R6, nullptr, nullptr, false);
}

// Round 12
// 3386.105 us; speedup vs baseline: 1.2441x; 1.2441x over previous
//
#include <hip/hip_runtime.h>
#include <math.h>

#define HB 8
#define TT 1024
#define NSTATE 16
#define NTT 6
#define NMM 8
#define MM (HB*TT)   /* 8192 rows */
#define EPSV 1e-5f
#define CHUNK 64
#define NCH (TT/CHUNK)   /* 16 */
#define AKS 128          /* attention keys staged per block iter */
#define VST 136          /* kv_split V-transpose LDS stride (halves) */

typedef _Float16 f16x8 __attribute__((ext_vector_type(8)));
typedef _Float16 f16x4 __attribute__((ext_vector_type(4)));
typedef _Float16 f16x2 __attribute__((ext_vector_type(2)));
typedef float f32x4_t __attribute__((ext_vector_type(4)));

static __device__ __forceinline__ void split8(const float4 a, const float4 b,
                                              f16x8& h, f16x8& l)
{
  float x[8] = {a.x, a.y, a.z, a.w, b.x, b.y, b.z, b.w};
#pragma unroll
  for (int i = 0; i < 8; i++) {
    _Float16 hi = (_Float16)x[i];
    h[i] = hi;
    l[i] = (_Float16)(x[i] - (float)hi);
  }
}

// async global->LDS, 16B per lane; LDS dest must be wave-uniform base.
static __device__ __forceinline__ void gload16(const _Float16* g, _Float16* l)
{
  __builtin_amdgcn_global_load_lds(
      (const __attribute__((address_space(1))) unsigned int*)g,
      (__attribute__((address_space(3))) unsigned int*)l, 16, 0, 0);
}

// ---------------------------------------------------------------------------
// Split layout: matrix [rows x K] fp32 -> [K/32 segs][rows][64 halves].
// ---------------------------------------------------------------------------
static __device__ __forceinline__ void store_split(_Float16* __restrict__ dst,
                                                   size_t row, int col, float v)
{
  const int cc = col & 31;
  const size_t o = ((size_t)(col >> 5) * MM + row) * 64
                 + (size_t)(((((cc >> 3) ^ ((int)row & 7)) * 8)) + (cc & 7));
  _Float16 hi = (_Float16)v;
  dst[o] = hi;
  dst[o ^ (size_t)32] = (_Float16)(v - (float)hi);
}

// paired variant: col0 must be even; writes 4B dwords (hi pair, lo pair)
static __device__ __forceinline__ void store_split2(_Float16* __restrict__ dst,
                                                    size_t row, int col0,
                                                    float v0, float v1)
{
  const int cc = col0 & 31;
  const size_t o = ((size_t)(col0 >> 5) * MM + row) * 64
                 + (size_t)(((((cc >> 3) ^ ((int)row & 7)) * 8)) + (cc & 7));
  _Float16 h0 = (_Float16)v0, h1 = (_Float16)v1;
  f16x2 hp = {h0, h1};
  f16x2 lp = {(_Float16)(v0 - (float)h0), (_Float16)(v1 - (float)h1)};
  *(f16x2*)&dst[o] = hp;
  *(f16x2*)&dst[o ^ (size_t)32] = lp;
}

static __device__ __forceinline__ void split_item(
    const float* __restrict__ src, int lda, int rows,
    _Float16* __restrict__ dst, int item)
{
  const int m = item % rows;
  const int seg = item / rows;
  const float* s = src + (size_t)m * lda + seg * 32;
  _Float16* d = dst + (size_t)item * 64;
  const int swz = m & 7;
#pragma unroll
  for (int g = 0; g < 4; g++) {
    float4 x0 = *(const float4*)&s[g * 8];
    float4 x1 = *(const float4*)&s[g * 8 + 4];
    f16x8 h, l;
    split8(x0, x1, h, l);
    const int u = (g ^ swz) * 8;
    *(f16x8*)&d[u] = h;
    *(f16x8*)&d[u ^ 32] = l;
  }
}

__global__ __launch_bounds__(256) void split_k(
    const float* __restrict__ src, int lda, int rows,
    _Float16* __restrict__ dst)
{
  split_item(src, lda, rows, dst, blockIdx.x * 256 + threadIdx.x);
}

// fused 3-region split (per mamba layer: inproj / xproj / dtw weights)
__global__ __launch_bounds__(256) void split3_k(
    const float* __restrict__ s0, int lda0, int rows0, _Float16* __restrict__ d0, int nb0,
    const float* __restrict__ s1, int lda1, int rows1, _Float16* __restrict__ d1, int nb1,
    const float* __restrict__ s2, int lda2, int rows2, _Float16* __restrict__ d2)
{
  const int bid = blockIdx.x;
  if (bid < nb0) {
    split_item(s0, lda0, rows0, d0, bid * 256 + threadIdx.x);
  } else if (bid < nb0 + nb1) {
    split_item(s1, lda1, rows1, d1, (bid - nb0) * 256 + threadIdx.x);
  } else {
    split_item(s2, lda2, rows2, d2, (bid - nb0 - nb1) * 256 + threadIdx.x);
  }
}

// fused 6-region split (one-time transformer weights + emb; c* are cum blocks)
__global__ __launch_bounds__(256) void split6_k(
    const float* __restrict__ s0, int lda0, int rows0, _Float16* __restrict__ d0, int c0,
    const float* __restrict__ s1, int lda1, int rows1, _Float16* __restrict__ d1, int c1,
    const float* __restrict__ s2, int lda2, int rows2, _Float16* __restrict__ d2, int c2,
    const float* __restrict__ s3, int lda3, int rows3, _Float16* __restrict__ d3, int c3,
    const float* __restrict__ s4, int lda4, int rows4, _Float16* __restrict__ d4, int c4,
    const float* __restrict__ s5, int lda5, int rows5, _Float16* __restrict__ d5)
{
  const int bid = blockIdx.x;
  if (bid < c0)      split_item(s0, lda0, rows0, d0, bid * 256 + threadIdx.x);
  else if (bid < c1) split_item(s1, lda1, rows1, d1, (bid - c0) * 256 + threadIdx.x);
  else if (bid < c2) split_item(s2, lda2, rows2, d2, (bid - c1) * 256 + threadIdx.x);
  else if (bid < c3) split_item(s3, lda3, rows3, d3, (bid - c2) * 256 + threadIdx.x);
  else if (bid < c4) split_item(s4, lda4, rows4, d4, (bid - c3) * 256 + threadIdx.x);
  else               split_item(s5, lda5, rows5, d5, (bid - c4) * 256 + threadIdx.x);
}

// ---------------------------------------------------------------------------
// K/V split producer for attention (unchanged).
// ---------------------------------------------------------------------------
__global__ __launch_bounds__(256) void kv_split_k(
    const float* __restrict__ qkv,
    _Float16* __restrict__ Ks, _Float16* __restrict__ Vs)
{
  __shared__ _Float16 Vthi[16 * VST], Vtlo[16 * VST];
  const int tid = threadIdx.x;
  const int bh = blockIdx.y;
  const int b = bh >> 3;
  const int h = bh & 7;
  const int kb0 = blockIdx.x * 128;

  const int kl = tid >> 1;
  const int half = tid & 1;
  const int key = kb0 + kl;
  const float* kp = qkv + (size_t)(b * TT + key) * 384 + 128 + h * 16 + half * 8;

  {
    float4 k0 = *(const float4*)&kp[0];
    float4 k1 = *(const float4*)&kp[4];
    f16x8 hh, ll;
    split8(k0, k1, hh, ll);
    const int p = (half + (key >> 1)) & 3;
    _Float16* kb = Ks + (((size_t)bh << 10) + key) * 32;
    *(f16x8*)&kb[p * 8] = hh;
    *(f16x8*)&kb[(p ^ 2) * 8] = ll;
  }
  {
    float4 v0 = *(const float4*)&kp[128];
    float4 v1 = *(const float4*)&kp[132];
    float xv[8] = {v0.x, v0.y, v0.z, v0.w, v1.x, v1.y, v1.z, v1.w};
#pragma unroll
    for (int j = 0; j < 8; j++) {
      const int d = half * 8 + j;
      _Float16 hi = (_Float16)xv[j];
      Vthi[d * VST + kl] = hi;
      Vtlo[d * VST + kl] = (_Float16)(xv[j] - (float)hi);
    }
  }
  __syncthreads();
  {
    const int d = tid >> 4;
    const int kg = tid & 15;
    f16x8 hh = *(const f16x8*)&Vthi[d * VST + kg * 8];
    f16x8 ll = *(const f16x8*)&Vtlo[d * VST + kg * 8];
    _Float16* vb = Vs + ((size_t)bh * 32 + d) * 1024 + kb0 + ((kg ^ d) * 8);
    *(f16x8*)&vb[0] = hh;
    *(f16x8*)&vb[16 * 1024] = ll;
  }
}

// ---------------------------------------------------------------------------
// fp16x3 split-precision MFMA GEMM, XCD-aware flattened grid (unchanged).
// ---------------------------------------------------------------------------
template<int TN>
__global__ __launch_bounds__(256, 4) void gemm_ps_t(
    const _Float16* __restrict__ Ap, int astr,
    const _Float16* __restrict__ Wp, int wstr,
    const float* __restrict__ bias,
    float* __restrict__ C,
    float* __restrict__ P,
    _Float16* __restrict__ Cs,
    int N, int K, int S, int act)
{
  __shared__ __align__(16) _Float16 As[128 * 64];
  __shared__ __align__(16) _Float16 Bs[TN * 64];
  const int tid = threadIdx.x;
  const int lane = tid & 63;
  const int w = tid >> 6;
  const int quad = lane >> 4;
  const int l16 = lane & 15;

  const int gx = N / TN;
  const int bid = blockIdx.x;
  const int xcd = bid & 7;
  const int i = bid >> 3;
  const int iq = i / gx;
  const int by = xcd * 8 + iq;
  const int bx = i - iq * gx;

  const int m0 = by * 128;
  const int n0 = bx * TN;
  const int z = blockIdx.z;
  const int nseg = K / 32;
  const int segb = z * (nseg / S);
  const int sege = segb + nseg / S;

  constexpr int MI = (TN == 128) ? 4 : 2;
  const int w0 = (TN == 128) ? (w & 1) : w;
  const int w1 = (TN == 128) ? (w >> 1) : 0;
  const int rowbase = (TN == 128) ? w0 * 64 : w0 * 32;

  f32x4_t acc[MI][4];
#pragma unroll
  for (int i2 = 0; i2 < MI; i2++)
#pragma unroll
    for (int j = 0; j < 4; j++)
#pragma unroll
      for (int r = 0; r < 4; r++) acc[i2][j][r] = 0.f;

  const int sw8 = (quad ^ (l16 & 7)) * 8;                 // hi unit offset
  const int abase = (rowbase + l16) * 64 + sw8;
  const int bbase = (w1 * 64 + l16) * 64 + sw8;
  const int wave64 = tid & 192;                            // wave*64

  for (int seg = segb; seg < sege; seg++) {
    const _Float16* At = Ap + ((size_t)seg * astr + m0) * 64;
    const _Float16* Bt = Wp + ((size_t)seg * wstr + n0) * 64;
    __syncthreads();
#pragma unroll
    for (int j = 0; j < 4; j++)
      gload16(At + (size_t)(j * 256 + tid) * 8, &As[(j * 256 + wave64) * 8]);
#pragma unroll
    for (int j = 0; j < TN / 32; j++)
      gload16(Bt + (size_t)(j * 256 + tid) * 8, &Bs[(j * 256 + wave64) * 8]);
    __syncthreads();

    f16x8 bh[4], bl[4];
#pragma unroll
    for (int ni = 0; ni < 4; ni++) {
      bh[ni] = *(const f16x8*)&Bs[bbase + ni * 1024];
      bl[ni] = *(const f16x8*)&Bs[(bbase ^ 32) + ni * 1024];
    }
#pragma unroll
    for (int mi = 0; mi < MI; mi++) {
      f16x8 ah = *(const f16x8*)&As[abase + mi * 1024];
      f16x8 al = *(const f16x8*)&As[(abase ^ 32) + mi * 1024];
#pragma unroll
      for (int ni = 0; ni < 4; ni++) {
        acc[mi][ni] = __builtin_amdgcn_mfma_f32_16x16x32_f16(ah, bh[ni], acc[mi][ni], 0, 0, 0);
        acc[mi][ni] = __builtin_amdgcn_mfma_f32_16x16x32_f16(ah, bl[ni], acc[mi][ni], 0, 0, 0);
        acc[mi][ni] = __builtin_amdgcn_mfma_f32_16x16x32_f16(al, bh[ni], acc[mi][ni], 0, 0, 0);
      }
    }
  }

  float* dst = (S == 1) ? C : (P + (size_t)z * MM * N);
#pragma unroll
  for (int ni = 0; ni < 4; ni++) {
    const int n = n0 + w1 * 64 + ni * 16 + l16;
    const float bv = (S == 1 && bias) ? bias[n] : 0.f;
#pragma unroll
    for (int mi = 0; mi < MI; mi++) {
      const int mbase = m0 + rowbase + mi * 16 + quad * 4;
#pragma unroll
      for (int r = 0; r < 4; r++) {
        float v = acc[mi][ni][r] + bv;
        if (S == 1) {
          if (act == 1) v = fmaxf(v, 0.f);
          else if (act == 2) v = fmaxf(v, 0.f) + log1pf(__expf(-fabsf(v)));
        }
        const int row = mbase + r;
        if (S == 1 && Cs) {
          store_split(Cs, (size_t)row, n, v);
        } else {
          dst[(size_t)row * N + n] = v;
        }
      }
    }
  }
}

// ---------------------------------------------------------------------------
// Split-K reduce: C(or split Cs) = act( sum_z P[z] + bias ).
// ---------------------------------------------------------------------------
__global__ __launch_bounds__(256) void reduce_k(
    const float* __restrict__ P, const float* __restrict__ bias,
    float* __restrict__ C, _Float16* __restrict__ Cs,
    _Float16* __restrict__ dta,
    int nmask, int nshift, int S, int act, int stride4)
{
  const int idx = blockIdx.x * 256 + threadIdx.x;
  float4 a = *(const float4*)&P[(size_t)idx * 4];
  for (int z = 1; z < S; z++) {
    float4 p = *(const float4*)&P[(size_t)(idx + (size_t)z * stride4) * 4];
    a.x += p.x; a.y += p.y; a.z += p.z; a.w += p.w;
  }
  if (bias) {
    float4 bv = *(const float4*)&bias[(idx * 4) & nmask];
    a.x += bv.x; a.y += bv.y; a.z += bv.z; a.w += bv.w;
  }
  if (act == 1) {
    a.x = fmaxf(a.x, 0.f); a.y = fmaxf(a.y, 0.f);
    a.z = fmaxf(a.z, 0.f); a.w = fmaxf(a.w, 0.f);
  } else if (act == 2) {
    a.x = fmaxf(a.x, 0.f) + log1pf(__expf(-fabsf(a.x)));
    a.y = fmaxf(a.y, 0.f) + log1pf(__expf(-fabsf(a.y)));
    a.z = fmaxf(a.z, 0.f) + log1pf(__expf(-fabsf(a.z)));
    a.w = fmaxf(a.w, 0.f) + log1pf(__expf(-fabsf(a.w)));
  }
  const int c0 = (idx * 4) & nmask;
  const size_t row = (size_t)(idx * 4) >> nshift;
  if (Cs) {
    store_split2(Cs, row, c0,     a.x, a.y);
    store_split2(Cs, row, c0 + 2, a.z, a.w);
  } else {
    *(float4*)&C[(size_t)idx * 4] = a;
  }
  if (dta && c0 < 32) {
    store_split2(dta, row, c0,     a.x, a.y);
    store_split2(dta, row, c0 + 2, a.z, a.w);
  }
}

// ---------------------------------------------------------------------------
// MFMA flash attention, swapped-operand QK (math validated in round 9:
// passed absmax 0.0). This version is FULLY HAND-UNROLLED — no runtime-
// indexed arrays (round-9's 146us regression was scratch spill from the
// un-unrolled shuffle loop, rule #20). 128 queries/block, grid (TT/128,64).
// ---------------------------------------------------------------------------
#define PASET(PA, I, V)                                                  \
  { _Float16 hi_ = (_Float16)(V);                                        \
    _Float16 lo_ = (_Float16)((V) - (float)hi_);                         \
    PA[I] = hisel ? hi_ : lo_; }

#define ATTN_STEP(QA, OACC, D0,D1,D2,D3,D4,D5,D6,D7)                     \
  {                                                                      \
    f32x4_t s;                                                           \
    s[0] = 0.f; s[1] = 0.f; s[2] = 0.f; s[3] = 0.f;                      \
    __builtin_amdgcn_s_setprio(1);                                       \
    s = __builtin_amdgcn_mfma_f32_16x16x32_f16(kfh, QA, s, 0, 0, 0);     \
    s = __builtin_amdgcn_mfma_f32_16x16x32_f16(kfl, QA, s, 0, 0, 0);     \
    __builtin_amdgcn_s_setprio(0);                                       \
    const float p0 = __expf(s[0]);                                       \
    const float p1 = __expf(s[1]);                                       \
    const float p2 = __expf(s[2]);                                       \
    const float p3 = __expf(s[3]);                                       \
    const float v0 = __shfl(p0, lo16);                                   \
    const float v1 = __shfl(p1, lo16);                                   \
    const float v2 = __shfl(p2, lo16);                                   \
    const float v3 = __shfl(p3, lo16);                                   \
    const float v4 = __shfl(p0, hi16);                                   \
    const float v5 = __shfl(p1, hi16);                                   \
    const float v6 = __shfl(p2, hi16);                                   \
    const float v7 = __shfl(p3, hi16);                                   \
    D0 += v0; D1 += v1; D2 += v2; D3 += v3;                              \
    D4 += v4; D5 += v5; D6 += v6; D7 += v7;                              \
    f16x8 pa;                                                            \
    PASET(pa, 0, v0) PASET(pa, 1, v1) PASET(pa, 2, v2) PASET(pa, 3, v3)  \
    PASET(pa, 4, v4) PASET(pa, 5, v5) PASET(pa, 6, v6) PASET(pa, 7, v7)  \
    __builtin_amdgcn_s_setprio(1);                                       \
    OACC = __builtin_amdgcn_mfma_f32_16x16x32_f16(pa, vfh, OACC, 0,0,0); \
    OACC = __builtin_amdgcn_mfma_f32_16x16x32_f16(pa, vfl, OACC, 0,0,0); \
    __builtin_amdgcn_s_setprio(0);                                       \
  }

__global__ __launch_bounds__(256) void attn_mfma_k(
    const float* __restrict__ qkv,
    const _Float16* __restrict__ Kg,
    const _Float16* __restrict__ Vg,
    _Float16* __restrict__ os)
{
  __shared__ __align__(16) _Float16 Klds[AKS * 32];     // [key][32]
  __shared__ __align__(16) _Float16 Vlds[32 * AKS];     // [plane*16+d][128]

  const int tid = threadIdx.x;
  const int lane = tid & 63;
  const int wv = tid >> 6;
  const int quad = lane >> 4;
  const int l16 = lane & 15;
  const int qh = quad & 1;
  const bool hisel = (quad < 2);
  const int bh = blockIdx.y;
  const int b = bh >> 3;
  const int h = bh & 7;
  const int qb0 = blockIdx.x * 128;
  const int wave64 = tid & 192;
  const int lo16 = qh * 32 + l16;        // shuffle src lanes
  const int hi16 = qh * 32 + 16 + l16;

  // Q frags (B-operand): n=query=l16, k-slots quad*8+j = dims qh*8+j, hi/lo
  f16x8 qa0, qa1;
  {
    const int qrow = qb0 + wv * 32 + l16;
    const float* qp = qkv + (size_t)(b * TT + qrow) * 384 + h * 16 + qh * 8;
    float4 x0 = *(const float4*)&qp[0];
    float4 x1 = *(const float4*)&qp[4];
    float xv[8] = {x0.x, x0.y, x0.z, x0.w, x1.x, x1.y, x1.z, x1.w};
#pragma unroll
    for (int j = 0; j < 8; j++) {
      float q = xv[j] * 0.25f;
      _Float16 hi = (_Float16)q;
      _Float16 lo = (_Float16)(q - (float)hi);
      qa0[j] = hisel ? hi : lo;
    }
  }
  {
    const int qrow = qb0 + wv * 32 + 16 + l16;
    const float* qp = qkv + (size_t)(b * TT + qrow) * 384 + h * 16 + qh * 8;
    float4 x0 = *(const float4*)&qp[0];
    float4 x1 = *(const float4*)&qp[4];
    float xv[8] = {x0.x, x0.y, x0.z, x0.w, x1.x, x1.y, x1.z, x1.w};
#pragma unroll
    for (int j = 0; j < 8; j++) {
      float q = xv[j] * 0.25f;
      _Float16 hi = (_Float16)q;
      _Float16 lo = (_Float16)(q - (float)hi);
      qa1[j] = hisel ? hi : lo;
    }
  }

  f32x4_t oacc0, oacc1;
  oacc0[0]=0.f; oacc0[1]=0.f; oacc0[2]=0.f; oacc0[3]=0.f;
  oacc1[0]=0.f; oacc1[1]=0.f; oacc1[2]=0.f; oacc1[3]=0.f;
  float d00=0.f,d01=0.f,d02=0.f,d03=0.f,d04=0.f,d05=0.f,d06=0.f,d07=0.f;
  float d10=0.f,d11=0.f,d12=0.f,d13=0.f,d14=0.f,d15=0.f,d16=0.f,d17=0.f;

  const _Float16* Kb = Kg + (((size_t)bh) << 10) * 32;
  const _Float16* Vb = Vg + ((size_t)bh * 32) * 1024;

  for (int ks = 0; ks < TT; ks += AKS) {
    __syncthreads();
    // stage K (8KB) + V (8KB) via global_load_lds
    {
      const _Float16* Kt = Kb + (size_t)ks * 32;
#pragma unroll
      for (int it = 0; it < 2; it++) {
        const int cb = it * 256 + tid;
        gload16(Kt + (size_t)cb * 8, &Klds[(it * 256 + wave64) * 8]);
      }
#pragma unroll
      for (int it = 0; it < 2; it++) {
        const int cb = it * 256 + tid;
        const int rowv = cb >> 4, co = cb & 15;
        gload16(Vb + (size_t)rowv * 1024 + ks + co * 8,
                &Vlds[(it * 256 + wave64) * 8]);
      }
    }
    __syncthreads();

#pragma unroll
    for (int kt = 0; kt < AKS; kt += 16) {
      const int key = kt + l16;
      const int ph = (qh + (key >> 1)) & 3;
      f16x8 kfh = *(const f16x8*)&Klds[key * 32 + ph * 8];
      f16x8 kfl = *(const f16x8*)&Klds[key * 32 + (ph ^ 2) * 8];
      const int vko = (kt + qh * 8) ^ (l16 * 8);
      f16x8 vfh = *(const f16x8*)&Vlds[l16 * 128 + vko];
      f16x8 vfl = *(const f16x8*)&Vlds[(16 + l16) * 128 + vko];

      ATTN_STEP(qa0, oacc0, d00,d01,d02,d03,d04,d05,d06,d07)
      ATTN_STEP(qa1, oacc1, d10,d11,d12,d13,d14,d15,d16,d17)
    }
  }

  // denominator: tree over key bits 1,2,4 in-register, bit 8 across qh.
  {
    const float g = ((d00+d01)+(d02+d03)) + ((d04+d05)+(d06+d07));
    const float lv = g + __shfl_xor(g, 16);
#pragma unroll
    for (int r = 0; r < 4; r++) {
      const float dq = __shfl(lv, quad * 4 + r);
      const float inv = 1.f / dq;
      const int qrow = qb0 + wv * 32 + quad * 4 + r;
      store_split(os, (size_t)(b * TT + qrow), h * 16 + l16, oacc0[r] * inv);
    }
  }
  {
    const float g = ((d10+d11)+(d12+d13)) + ((d14+d15)+(d16+d17));
    const float lv = g + __shfl_xor(g, 16);
#pragma unroll
    for (int r = 0; r < 4; r++) {
      const float dq = __shfl(lv, quad * 4 + r);
      const float inv = 1.f / dq;
      const int qrow = qb0 + wv * 32 + 16 + quad * 4 + r;
      store_split(os, (size_t)(b * TT + qrow), h * 16 + l16, oacc1[r] * inv);
    }
  }
}

// ---------------------------------------------------------------------------
// out = LN(a + bvec) * w + bb  (fp32 out + fused split out)
// ---------------------------------------------------------------------------
__global__ __launch_bounds__(256) void add_ln_k(
    const float* __restrict__ a, const float* __restrict__ bvec,
    const float* __restrict__ w, const float* __restrict__ bb,
    float* __restrict__ out, _Float16* __restrict__ outs)
{
  const int tid = threadIdx.x;
  const int wave = tid >> 6, lane = tid & 63;
  const size_t row = (size_t)blockIdx.x * 4 + wave;
  const float* pa = a + row * 128;
  const float* pb = bvec + row * 128;
  float v0 = pa[lane] + pb[lane];
  float v1 = pa[lane + 64] + pb[lane + 64];
  float s1 = v0 + v1, s2 = v0 * v0 + v1 * v1;
#pragma unroll
  for (int off = 32; off; off >>= 1) {
    s1 += __shfl_down(s1, off);
    s2 += __shfl_down(s2, off);
  }
  s1 = __shfl(s1, 0); s2 = __shfl(s2, 0);
  const float mean = s1 * (1.f / 128.f);
  const float var = s2 * (1.f / 128.f) - mean * mean;
  const float rs = rsqrtf(var + EPSV);
  const float o0 = (v0 - mean) * rs * w[lane] + bb[lane];
  const float o1 = (v1 - mean) * rs * w[lane + 64] + bb[lane + 64];
  out[row * 128 + lane] = o0;
  out[row * 128 + lane + 64] = o1;
  store_split(outs, row, lane, o0);
  store_split(outs, row, lane + 64, o1);
}

// ---------------------------------------------------------------------------
// Depthwise causal conv (DC=4) + SiLU; 4 t-steps x 2 channels per thread.
// ---------------------------------------------------------------------------
__global__ __launch_bounds__(256) void conv_silu_k(
    const float* __restrict__ xz, const float* __restrict__ cw,
    const float* __restrict__ cb, float* __restrict__ out,
    _Float16* __restrict__ outs)
{
  const int idx = blockIdx.x * 256 + threadIdx.x;   // over (MM/4)*512
  const int di = (idx & 511) * 2;
  const int tg = idx >> 9;
  const int m0 = tg * 4;
  const int t0 = m0 & (TT - 1);

  float wa[4], wb[4];
#pragma unroll
  for (int k = 0; k < 4; k++) {
    wa[k] = cw[di * 4 + k];
    wb[k] = cw[di * 4 + 4 + k];
  }
  const float b0 = cb[di], b1 = cb[di + 1];

  float2 xr[7];
#pragma unroll
  for (int j = 0; j < 7; j++) {
    if (t0 + j - 3 >= 0) {
      xr[j] = *(const float2*)&xz[(size_t)(m0 + j - 3) * 2048 + di];
    } else {
      xr[j].x = 0.f; xr[j].y = 0.f;
    }
  }

#pragma unroll
  for (int j = 0; j < 4; j++) {
    float a0 = b0, a1 = b1;
#pragma unroll
    for (int k = 0; k < 4; k++) {
      a0 += xr[j + k].x * wa[k];
      a1 += xr[j + k].y * wb[k];
    }
    const float y0 = a0 / (1.f + __expf(-a0));
    const float y1 = a1 / (1.f + __expf(-a1));
    float2 yo = {y0, y1};
    const size_t m = (size_t)(m0 + j);
    *(float2*)&out[m * 1024 + di] = yo;
    store_split2(outs, m, di, y0, y1);
  }
}

// ---------------------------------------------------------------------------
// Chunked selective scan, phase A: local scan, emit P=prod(dA), S=local h.
// ---------------------------------------------------------------------------
__global__ __launch_bounds__(64) void scan_partial_k(
    const float* __restrict__ dt,
    const float* __restrict__ dbc,
    const float* __restrict__ xi,
    const float* __restrict__ Alog,
    float* __restrict__ Pb, float* __restrict__ Sb)
{
  const int slice = blockIdx.x & 15;
  const int c = blockIdx.x >> 4;
  const int b = blockIdx.y;
  const int di = slice * 64 + threadIdx.x;

  float A[NSTATE];
#pragma unroll
  for (int n = 0; n < NSTATE; n++) A[n] = -__expf(Alog[di * NSTATE + n]);
  float h[NSTATE], P[NSTATE];
#pragma unroll
  for (int n = 0; n < NSTATE; n++) { h[n] = 0.f; P[n] = 1.f; }

  const size_t m0 = (size_t)b * TT + (size_t)c * CHUNK;
  for (int t = 0; t < CHUNK; t++) {
    const size_t m = m0 + t;
    const float dtv = dt[m * 1024 + di];
    const float xv  = xi[m * 1024 + di];
    const float dtx = dtv * xv;
#pragma unroll
    for (int n = 0; n < NSTATE; n++) {
      const float Bv = dbc[m * 64 + 32 + n];
      const float dA = __expf(dtv * A[n]);
      h[n] = h[n] * dA + dtx * Bv;
      P[n] *= dA;
    }
  }
  const size_t base = (((size_t)b * NCH + c) * NSTATE) * 1024 + di;
#pragma unroll
  for (int n = 0; n < NSTATE; n++) {
    Pb[base + (size_t)n * 1024] = P[n];
    Sb[base + (size_t)n * 1024] = h[n];
  }
}

// ---------------------------------------------------------------------------
// Phase B: sequential chunk fix-up, one thread per (b, di, n).
// ---------------------------------------------------------------------------
__global__ __launch_bounds__(256) void scan_fix_k(
    float* __restrict__ Pb, const float* __restrict__ Sb)
{
  const int idx = blockIdx.x * 256 + threadIdx.x;   // over HB*16*1024
  const int di = idx & 1023;
  const int n  = (idx >> 10) & 15;
  const int b  = idx >> 14;
  float h = 0.f;
  for (int c = 0; c < NCH; c++) {
    const size_t base = (((size_t)b * NCH + c) * NSTATE + n) * 1024 + di;
    const float P = Pb[base];
    const float S = Sb[base];
    Pb[base] = h;
    h = P * h + S;
  }
}

// ---------------------------------------------------------------------------
// Phase C: re-run each chunk from h_in; y = dot(h,C) + D*x; *= silu(z).
// ---------------------------------------------------------------------------
__global__ __launch_bounds__(64) void scan_final_k(
    const float* __restrict__ dt,
    const float* __restrict__ dbc,
    const float* __restrict__ xi,
    const float* __restrict__ xz,
    const float* __restrict__ Alog,
    const float* __restrict__ Dp,
    const float* __restrict__ Hin,
    _Float16* __restrict__ Y)
{
  const int slice = blockIdx.x & 15;
  const int c = blockIdx.x >> 4;
  const int b = blockIdx.y;
  const int di = slice * 64 + threadIdx.x;

  float A[NSTATE];
#pragma unroll
  for (int n = 0; n < NSTATE; n++) A[n] = -__expf(Alog[di * NSTATE + n]);
  const float Dv = Dp[di];
  float h[NSTATE];
  const size_t hbase = (((size_t)b * NCH + c) * NSTATE) * 1024 + di;
#pragma unroll
  for (int n = 0; n < NSTATE; n++) h[n] = Hin[hbase + (size_t)n * 1024];

  const size_t m0 = (size_t)b * TT + (size_t)c * CHUNK;
  for (int t = 0; t < CHUNK; t++) {
    const size_t m = m0 + t;
    const float dtv = dt[m * 1024 + di];
    const float xv  = xi[m * 1024 + di];
    const float zv  = xz[m * 2048 + 1024 + di];
    const float dtx = dtv * xv;
    float y = 0.f;
#pragma unroll
    for (int n = 0; n < NSTATE; n++) {
      const float Bv = dbc[m * 64 + 32 + n];
      const float Cv = dbc[m * 64 + 48 + n];
      const float dA = __expf(dtv * A[n]);
      h[n] = h[n] * dA + dtx * Bv;
      y += h[n] * Cv;
    }
    y += Dv * xv;
    y *= zv / (1.f + __expf(-zv));
    store_split(Y, m, di, y);
  }
}

// ---------------------------------------------------------------------------
extern "C" void kernel_launch(void* const* d_in, const int* in_sizes, int n_in,
                              void* d_out, int out_size, void* d_ws, size_t ws_size,
                              hipStream_t stream)
{
  (void)in_sizes; (void)n_in; (void)out_size; (void)ws_size;
  const float* emb      = (const float*)d_in[0];
  const float* t_wqkv   = (const float*)d_in[1];
  const float* t_bqkv   = (const float*)d_in[2];
  const float* t_wo     = (const float*)d_in[3];
  const float* t_bo     = (const float*)d_in[4];
  const float* t_ln1w   = (const float*)d_in[5];
  const float* t_ln1b   = (const float*)d_in[6];
  const float* t_w1     = (const float*)d_in[7];
  const float* t_b1     = (const float*)d_in[8];
  const float* t_w2     = (const float*)d_in[9];
  const float* t_b2     = (const float*)d_in[10];
  const float* t_ln2w   = (const float*)d_in[11];
  const float* t_ln2b   = (const float*)d_in[12];
  const float* w_in     = (const float*)d_in[13];
  const float* b_in     = (const float*)d_in[14];
  const float* m_inproj = (const float*)d_in[15];
  const float* m_convw  = (const float*)d_in[16];
  const float* m_convb  = (const float*)d_in[17];
  const float* m_xproj  = (const float*)d_in[18];
  const float* m_dtw    = (const float*)d_in[19];
  const float* m_dtb    = (const float*)d_in[20];
  const float* m_Alog   = (const float*)d_in[21];
  const float* m_D      = (const float*)d_in[22];
  const float* m_outproj= (const float*)d_in[23];
  const float* w_out    = (const float*)d_in[24];
  const float* b_out    = (const float*)d_in[25];

  // Workspace: EXACTLY the round-0 footprint (MM*6208 floats, 203.4 MB).
  float* ws = (float*)d_ws;
  float* R1 = ws;                         // MM*512   x fp32 | mamba xos/xcs
  float* R2 = ws + (size_t)MM * 512;      // MM*512   wo partials + KV split | mamba xcs/xos
  float* R3 = ws + (size_t)MM * 1024;     // MM*2048  qkv | w1 split | xz | outproj partials
  float* R4 = ws + (size_t)MM * 3072;     // MM*1024  transformer weight splits | xi fp32
  float* R5 = ws + (size_t)MM * 4096;     // MM*1024  wo/w2 out fp32 | dt fp32
  float* R6 = ws + (size_t)MM * 5120;     // MM*1024  ASP1 + w2 partials | xi-split/DTA/Y-split
  float* R7 = ws + (size_t)MM * 6144;     // MM*64    dbc

  // transformer weight splits in R4
  _Float16* TWQKV = (_Float16*)R4;                    // 6*384  x 128
  _Float16* TWO   = TWQKV + (size_t)294912 * 2;       // 6*128  x 128
  _Float16* TW1   = TWO   + (size_t)98304 * 2;        // 6*2048 x 128
  _Float16* TW2   = TW1   + (size_t)1572864 * 2;      // 6*128  x 2048
  _Float16* TWIN  = TW2   + (size_t)1572864 * 2;      // 512    x 128  (ends at MM*440)

  _Float16* ASP1 = (_Float16*)R6;                     // M x 128 split
  _Float16* XIS  = (_Float16*)R6;                     // M x 1024 split (mamba)
  _Float16* DTA  = (_Float16*)R6;                     // M x 32 split
  _Float16* YSP  = (_Float16*)R6;                     // M x 1024 split (scan out)

  // attention K/V split buffers in R2 tail (wo partials use R2[0:MM*256))
  _Float16* KG = (_Float16*)(R2 + (size_t)MM * 256);  // 64*1024*32 halves (4MB)
  _Float16* VG = (_Float16*)(R2 + (size_t)MM * 320);  // 64*32*1024 halves (4MB)

  dim3 blk(256);
  auto split = [&](const float* src, int lda, int rows, int K, _Float16* dst) {
    hipLaunchKernelGGL(split_k, dim3(rows * (K / 32) / 256), blk, 0, stream,
                       src, lda, rows, dst);
  };
  auto gemm = [&](const _Float16* Ap, const _Float16* Wp, int wstr,
                  const float* bias, float* C, int N, int K, int act,
                  int S, float* P, _Float16* Cs, _Float16* dta, bool tn64) {
    dim3 g((N / (tn64 ? 64 : 128)) * (MM / 128), 1, S);
    if (tn64)
      hipLaunchKernelGGL(gemm_ps_t<64>, g, blk, 0, stream,
                         Ap, MM, Wp, wstr, bias, C, P, Cs, N, K, S, act);
    else
      hipLaunchKernelGGL(gemm_ps_t<128>, g, blk, 0, stream,
                         Ap, MM, Wp, wstr, bias, C, P, Cs, N, K, S, act);
    if (S > 1) {
      int stride4 = (int)((size_t)MM * N / 4);
      hipLaunchKernelGGL(reduce_k, dim3(stride4 / 256), blk, 0, stream,
                         P, bias, C, Cs, dta, N - 1, __builtin_ctz(N), S, act,
                         stride4);
    }
  };

  // ---- one-time splits, single launch (wqkv|wo|w1|w2|w_in|emb) ----
  hipLaunchKernelGGL(split6_k, dim3(568), blk, 0, stream,
      t_wqkv, 128,  2304, TWQKV,  36,
      t_wo,   128,   768, TWO,    48,
      t_w1,   128, 12288, TW1,   240,
      t_w2,  2048,   768, TW2,   432,
      w_in,   128,   512, TWIN,  440,
      emb,    128,    MM, ASP1);

  // ---- transformer stack ----
  const float* x = emb;
  for (int l = 0; l < NTT; l++) {
    // qkv: N=384 K=128, plain fp32 out -> R3
    gemm(ASP1, TWQKV + (size_t)l * 384 * 64, 2304, t_bqkv + l * 384,
         R3, 384, 128, 0, 1, nullptr, nullptr, nullptr, false);
    // K/V -> split buffers (coalesced)
    hipLaunchKernelGGL(kv_split_k, dim3(8, HB * 8), blk, 0, stream,
                       R3, KG, VG);
    // attention -> split ASP1 (wo's A)
    hipLaunchKernelGGL(attn_mfma_k, dim3(TT / 128, HB * 8), blk, 0, stream,
                       R3, KG, VG, ASP1);
    // wo: N=128 K=128, S=2, partials in R2 head
    gemm(ASP1, TWO + (size_t)l * 128 * 64, 768, t_bo + l * 128,
         R5, 128, 128, 0, 2, R2, nullptr, nullptr, true);
    hipLaunchKernelGGL(add_ln_k, dim3(MM / 4), blk, 0, stream,
                       x, R5, t_ln1w + l * 128, t_ln1b + l * 128, R1, ASP1);
    // w1: N=2048 K=128, relu, split-only output overlaid in R3 (w2's A)
    gemm(ASP1, TW1 + (size_t)l * 2048 * 64, 12288, t_b1 + l * 2048,
         R3, 2048, 128, 1, 1, nullptr, (_Float16*)R3, nullptr, false);
    // w2: N=128 K=2048, S=8, partials fill R6 (ASP1 dead here)
    gemm((_Float16*)R3, TW2 + (size_t)l * 128 * 64, 768, t_b2 + l * 128,
         R5, 128, 2048, 0, 8, R6, nullptr, nullptr, false);
    hipLaunchKernelGGL(add_ln_k, dim3(MM / 4), blk, 0, stream,
                       R1, R5, t_ln2w + l * 128, t_ln2b + l * 128, R1, ASP1);
    x = R1;
  }

  // w_in: N=512 K=128, split-only output -> R2 (mamba x)
  gemm(ASP1, TWIN, 512, b_in, R2, 512, 128, 0, 1, nullptr, (_Float16*)R2,
       nullptr, false);

  float* xcs = R2;
  float* xos = R1;
  for (int l = 0; l < NMM; l++) {
    // per-layer mamba weight splits into dead slivers of xos
    _Float16* WIs = (_Float16*)(xos + (size_t)MM * 256);
    _Float16* WXs = (_Float16*)(xos + (size_t)MM * 384);
    _Float16* WDs = (_Float16*)(xos + (size_t)MM * 392);
    _Float16* WOs = (_Float16*)(xos + (size_t)MM * 256);  // after scan_fix
    hipLaunchKernelGGL(split3_k, dim3(140), blk, 0, stream,
        m_inproj + (size_t)l * 2048 * 512, 512, 2048, WIs, 128,
        m_xproj  + (size_t)l * 64 * 1024, 1024,   64, WXs,   8,
        m_dtw    + (size_t)l * 1024 * 32,   32, 1024, WDs);

    // inproj: N=2048 K=512, fp32 out (conv + z) -> R3
    gemm((_Float16*)xcs, WIs, 2048, nullptr,
         R3, 2048, 512, 0, 1, nullptr, nullptr, nullptr, false);
    hipLaunchKernelGGL(conv_silu_k, dim3(MM / 2), blk, 0, stream,
                       R3, m_convw + (size_t)l * 1024 * 4, m_convb + l * 1024,
                       R4, XIS);
    // xproj: N=64 K=1024, S=4, partials xos[0:256); reduce also emits DTA
    gemm(XIS, WXs, 64, nullptr,
         R7, 64, 1024, 0, 4, xos, nullptr, DTA, true);
    // dtw: N=1024 K=32, softplus -> R5
    gemm(DTA, WDs, 1024, m_dtb + l * 1024,
         R5, 1024, 32, 2, 1, nullptr, nullptr, nullptr, false);

    float* Pb = xos;
    float* Sb = xos + (size_t)MM * 256;
    hipLaunchKernelGGL(scan_partial_k, dim3(16 * NCH, HB), dim3(64), 0, stream,
                       R5, R7, R4, m_Alog + (size_t)l * 1024 * 16, Pb, Sb);
    hipLaunchKernelGGL(scan_fix_k, dim3(HB * NSTATE * 1024 / 256), blk, 0,
                       stream, Pb, Sb);
    // outproj weight split now (Sb dead, Pb still live for scan_final)
    split(m_outproj + (size_t)l * 512 * 1024, 1024, 512, 1024, WOs);
    hipLaunchKernelGGL(scan_final_k, dim3(16 * NCH, HB), dim3(64), 0, stream,
                       R5, R7, R4, R3,
                       m_Alog + (size_t)l * 1024 * 16, m_D + l * 1024, Pb, YSP);

    // outproj: N=512 K=1024, S=2, partials R3 (xz dead), split out -> xos
    gemm(YSP, WOs, 512, nullptr,
         R5, 512, 1024, 0, 2, R3, (_Float16*)xos, nullptr, false);
    float* ts = xcs; xcs = xos; xos = ts;
  }

  // w_out: N=128 K=512, S=4, partials in R6 (dead); weight split in xos (dead)
  _Float16* WOUTs = (_Float16*)xos;
  split(w_out, 512, 128, 512, WOUTs);
  gemm((_Float16*)xcs, WOUTs, 128, b_out,
       (float*)d_out, 128, 512, 0, 4, R6, nullptr, nullptr, false);
}

// Round 13
// 3246.482 us; speedup vs baseline: 1.2976x; 1.0430x over previous
//
#include <hip/hip_runtime.h>
#include <math.h>

#define HB 8
#define TT 1024
#define NSTATE 16
#define NTT 6
#define NMM 8
#define MM (HB*TT)   /* 8192 rows */
#define EPSV 1e-5f
#define CHUNK 64
#define NCH (TT/CHUNK)   /* 16 */
#define AKS 128          /* attention keys staged per block iter */
#define VST 136          /* kv_split V-transpose LDS stride (halves) */

typedef _Float16 f16x8 __attribute__((ext_vector_type(8)));
typedef _Float16 f16x4 __attribute__((ext_vector_type(4)));
typedef _Float16 f16x2 __attribute__((ext_vector_type(2)));
typedef float f32x4_t __attribute__((ext_vector_type(4)));

static __device__ __forceinline__ void split8(const float4 a, const float4 b,
                                              f16x8& h, f16x8& l)
{
  float x[8] = {a.x, a.y, a.z, a.w, b.x, b.y, b.z, b.w};
#pragma unroll
  for (int i = 0; i < 8; i++) {
    _Float16 hi = (_Float16)x[i];
    h[i] = hi;
    l[i] = (_Float16)(x[i] - (float)hi);
  }
}

// async global->LDS, 16B per lane; LDS dest must be wave-uniform base.
static __device__ __forceinline__ void gload16(const _Float16* g, _Float16* l)
{
  __builtin_amdgcn_global_load_lds(
      (const __attribute__((address_space(1))) unsigned int*)g,
      (__attribute__((address_space(3))) unsigned int*)l, 16, 0, 0);
}

// ---------------------------------------------------------------------------
// Split layout: matrix [rows x K] fp32 -> [K/32 segs][rows][64 halves].
// ---------------------------------------------------------------------------
static __device__ __forceinline__ void store_split(_Float16* __restrict__ dst,
                                                   size_t row, int col, float v)
{
  const int cc = col & 31;
  const size_t o = ((size_t)(col >> 5) * MM + row) * 64
                 + (size_t)(((((cc >> 3) ^ ((int)row & 7)) * 8)) + (cc & 7));
  _Float16 hi = (_Float16)v;
  dst[o] = hi;
  dst[o ^ (size_t)32] = (_Float16)(v - (float)hi);
}

// paired variant: col0 must be even; writes 4B dwords (hi pair, lo pair)
static __device__ __forceinline__ void store_split2(_Float16* __restrict__ dst,
                                                    size_t row, int col0,
                                                    float v0, float v1)
{
  const int cc = col0 & 31;
  const size_t o = ((size_t)(col0 >> 5) * MM + row) * 64
                 + (size_t)(((((cc >> 3) ^ ((int)row & 7)) * 8)) + (cc & 7));
  _Float16 h0 = (_Float16)v0, h1 = (_Float16)v1;
  f16x2 hp = {h0, h1};
  f16x2 lp = {(_Float16)(v0 - (float)h0), (_Float16)(v1 - (float)h1)};
  *(f16x2*)&dst[o] = hp;
  *(f16x2*)&dst[o ^ (size_t)32] = lp;
}

// reconstruct value from split buffer (hi+lo)
static __device__ __forceinline__ float load_split(const _Float16* __restrict__ src,
                                                   size_t row, int col)
{
  const int cc = col & 31;
  const size_t o = ((size_t)(col >> 5) * MM + row) * 64
                 + (size_t)(((((cc >> 3) ^ ((int)row & 7)) * 8)) + (cc & 7));
  return (float)src[o] + (float)src[o ^ (size_t)32];
}

static __device__ __forceinline__ void split_item(
    const float* __restrict__ src, int lda, int rows,
    _Float16* __restrict__ dst, int item)
{
  const int m = item % rows;
  const int seg = item / rows;
  const float* s = src + (size_t)m * lda + seg * 32;
  _Float16* d = dst + (size_t)item * 64;
  const int swz = m & 7;
#pragma unroll
  for (int g = 0; g < 4; g++) {
    float4 x0 = *(const float4*)&s[g * 8];
    float4 x1 = *(const float4*)&s[g * 8 + 4];
    f16x8 h, l;
    split8(x0, x1, h, l);
    const int u = (g ^ swz) * 8;
    *(f16x8*)&d[u] = h;
    *(f16x8*)&d[u ^ 32] = l;
  }
}

__global__ __launch_bounds__(256) void split_k(
    const float* __restrict__ src, int lda, int rows,
    _Float16* __restrict__ dst)
{
  split_item(src, lda, rows, dst, blockIdx.x * 256 + threadIdx.x);
}

// fused 3-region split (per mamba layer: inproj / xproj / dtw weights)
__global__ __launch_bounds__(256) void split3_k(
    const float* __restrict__ s0, int lda0, int rows0, _Float16* __restrict__ d0, int nb0,
    const float* __restrict__ s1, int lda1, int rows1, _Float16* __restrict__ d1, int nb1,
    const float* __restrict__ s2, int lda2, int rows2, _Float16* __restrict__ d2)
{
  const int bid = blockIdx.x;
  if (bid < nb0) {
    split_item(s0, lda0, rows0, d0, bid * 256 + threadIdx.x);
  } else if (bid < nb0 + nb1) {
    split_item(s1, lda1, rows1, d1, (bid - nb0) * 256 + threadIdx.x);
  } else {
    split_item(s2, lda2, rows2, d2, (bid - nb0 - nb1) * 256 + threadIdx.x);
  }
}

// fused 6-region split (one-time transformer weights + emb; c* are cum blocks)
__global__ __launch_bounds__(256) void split6_k(
    const float* __restrict__ s0, int lda0, int rows0, _Float16* __restrict__ d0, int c0,
    const float* __restrict__ s1, int lda1, int rows1, _Float16* __restrict__ d1, int c1,
    const float* __restrict__ s2, int lda2, int rows2, _Float16* __restrict__ d2, int c2,
    const float* __restrict__ s3, int lda3, int rows3, _Float16* __restrict__ d3, int c3,
    const float* __restrict__ s4, int lda4, int rows4, _Float16* __restrict__ d4, int c4,
    const float* __restrict__ s5, int lda5, int rows5, _Float16* __restrict__ d5)
{
  const int bid = blockIdx.x;
  if (bid < c0)      split_item(s0, lda0, rows0, d0, bid * 256 + threadIdx.x);
  else if (bid < c1) split_item(s1, lda1, rows1, d1, (bid - c0) * 256 + threadIdx.x);
  else if (bid < c2) split_item(s2, lda2, rows2, d2, (bid - c1) * 256 + threadIdx.x);
  else if (bid < c3) split_item(s3, lda3, rows3, d3, (bid - c2) * 256 + threadIdx.x);
  else if (bid < c4) split_item(s4, lda4, rows4, d4, (bid - c3) * 256 + threadIdx.x);
  else               split_item(s5, lda5, rows5, d5, (bid - c4) * 256 + threadIdx.x);
}

// ---------------------------------------------------------------------------
// K/V split producer for attention (unchanged).
// ---------------------------------------------------------------------------
__global__ __launch_bounds__(256) void kv_split_k(
    const float* __restrict__ qkv,
    _Float16* __restrict__ Ks, _Float16* __restrict__ Vs)
{
  __shared__ _Float16 Vthi[16 * VST], Vtlo[16 * VST];
  const int tid = threadIdx.x;
  const int bh = blockIdx.y;
  const int b = bh >> 3;
  const int h = bh & 7;
  const int kb0 = blockIdx.x * 128;

  const int kl = tid >> 1;
  const int half = tid & 1;
  const int key = kb0 + kl;
  const float* kp = qkv + (size_t)(b * TT + key) * 384 + 128 + h * 16 + half * 8;

  {
    float4 k0 = *(const float4*)&kp[0];
    float4 k1 = *(const float4*)&kp[4];
    f16x8 hh, ll;
    split8(k0, k1, hh, ll);
    const int p = (half + (key >> 1)) & 3;
    _Float16* kb = Ks + (((size_t)bh << 10) + key) * 32;
    *(f16x8*)&kb[p * 8] = hh;
    *(f16x8*)&kb[(p ^ 2) * 8] = ll;
  }
  {
    float4 v0 = *(const float4*)&kp[128];
    float4 v1 = *(const float4*)&kp[132];
    float xv[8] = {v0.x, v0.y, v0.z, v0.w, v1.x, v1.y, v1.z, v1.w};
#pragma unroll
    for (int j = 0; j < 8; j++) {
      const int d = half * 8 + j;
      _Float16 hi = (_Float16)xv[j];
      Vthi[d * VST + kl] = hi;
      Vtlo[d * VST + kl] = (_Float16)(xv[j] - (float)hi);
    }
  }
  __syncthreads();
  {
    const int d = tid >> 4;
    const int kg = tid & 15;
    f16x8 hh = *(const f16x8*)&Vthi[d * VST + kg * 8];
    f16x8 ll = *(const f16x8*)&Vtlo[d * VST + kg * 8];
    _Float16* vb = Vs + ((size_t)bh * 32 + d) * 1024 + kb0 + ((kg ^ d) * 8);
    *(f16x8*)&vb[0] = hh;
    *(f16x8*)&vb[16 * 1024] = ll;
  }
}

// ---------------------------------------------------------------------------
// fp16x3 split-precision MFMA GEMM, XCD-aware flattened grid (unchanged).
// ---------------------------------------------------------------------------
template<int TN>
__global__ __launch_bounds__(256, 4) void gemm_ps_t(
    const _Float16* __restrict__ Ap, int astr,
    const _Float16* __restrict__ Wp, int wstr,
    const float* __restrict__ bias,
    float* __restrict__ C,
    float* __restrict__ P,
    _Float16* __restrict__ Cs,
    int N, int K, int S, int act)
{
  __shared__ __align__(16) _Float16 As[128 * 64];
  __shared__ __align__(16) _Float16 Bs[TN * 64];
  const int tid = threadIdx.x;
  const int lane = tid & 63;
  const int w = tid >> 6;
  const int quad = lane >> 4;
  const int l16 = lane & 15;

  const int gx = N / TN;
  const int bid = blockIdx.x;
  const int xcd = bid & 7;
  const int i = bid >> 3;
  const int iq = i / gx;
  const int by = xcd * 8 + iq;
  const int bx = i - iq * gx;

  const int m0 = by * 128;
  const int n0 = bx * TN;
  const int z = blockIdx.z;
  const int nseg = K / 32;
  const int segb = z * (nseg / S);
  const int sege = segb + nseg / S;

  constexpr int MI = (TN == 128) ? 4 : 2;
  const int w0 = (TN == 128) ? (w & 1) : w;
  const int w1 = (TN == 128) ? (w >> 1) : 0;
  const int rowbase = (TN == 128) ? w0 * 64 : w0 * 32;

  f32x4_t acc[MI][4];
#pragma unroll
  for (int i2 = 0; i2 < MI; i2++)
#pragma unroll
    for (int j = 0; j < 4; j++)
#pragma unroll
      for (int r = 0; r < 4; r++) acc[i2][j][r] = 0.f;

  const int sw8 = (quad ^ (l16 & 7)) * 8;                 // hi unit offset
  const int abase = (rowbase + l16) * 64 + sw8;
  const int bbase = (w1 * 64 + l16) * 64 + sw8;
  const int wave64 = tid & 192;                            // wave*64

  for (int seg = segb; seg < sege; seg++) {
    const _Float16* At = Ap + ((size_t)seg * astr + m0) * 64;
    const _Float16* Bt = Wp + ((size_t)seg * wstr + n0) * 64;
    __syncthreads();
#pragma unroll
    for (int j = 0; j < 4; j++)
      gload16(At + (size_t)(j * 256 + tid) * 8, &As[(j * 256 + wave64) * 8]);
#pragma unroll
    for (int j = 0; j < TN / 32; j++)
      gload16(Bt + (size_t)(j * 256 + tid) * 8, &Bs[(j * 256 + wave64) * 8]);
    __syncthreads();

    f16x8 bh[4], bl[4];
#pragma unroll
    for (int ni = 0; ni < 4; ni++) {
      bh[ni] = *(const f16x8*)&Bs[bbase + ni * 1024];
      bl[ni] = *(const f16x8*)&Bs[(bbase ^ 32) + ni * 1024];
    }
#pragma unroll
    for (int mi = 0; mi < MI; mi++) {
      f16x8 ah = *(const f16x8*)&As[abase + mi * 1024];
      f16x8 al = *(const f16x8*)&As[(abase ^ 32) + mi * 1024];
#pragma unroll
      for (int ni = 0; ni < 4; ni++) {
        acc[mi][ni] = __builtin_amdgcn_mfma_f32_16x16x32_f16(ah, bh[ni], acc[mi][ni], 0, 0, 0);
        acc[mi][ni] = __builtin_amdgcn_mfma_f32_16x16x32_f16(ah, bl[ni], acc[mi][ni], 0, 0, 0);
        acc[mi][ni] = __builtin_amdgcn_mfma_f32_16x16x32_f16(al, bh[ni], acc[mi][ni], 0, 0, 0);
      }
    }
  }

  float* dst = (S == 1) ? C : (P + (size_t)z * MM * N);
#pragma unroll
  for (int ni = 0; ni < 4; ni++) {
    const int n = n0 + w1 * 64 + ni * 16 + l16;
    const float bv = (S == 1 && bias) ? bias[n] : 0.f;
#pragma unroll
    for (int mi = 0; mi < MI; mi++) {
      const int mbase = m0 + rowbase + mi * 16 + quad * 4;
#pragma unroll
      for (int r = 0; r < 4; r++) {
        float v = acc[mi][ni][r] + bv;
        if (S == 1) {
          if (act == 1) v = fmaxf(v, 0.f);
          else if (act == 2) v = fmaxf(v, 0.f) + log1pf(__expf(-fabsf(v)));
        }
        const int row = mbase + r;
        if (S == 1 && Cs) {
          store_split(Cs, (size_t)row, n, v);
        } else {
          dst[(size_t)row * N + n] = v;
        }
      }
    }
  }
}

// ---------------------------------------------------------------------------
// Split-K reduce: C(or split Cs) = act( sum_z P[z] + bias ).
// ---------------------------------------------------------------------------
__global__ __launch_bounds__(256) void reduce_k(
    const float* __restrict__ P, const float* __restrict__ bias,
    float* __restrict__ C, _Float16* __restrict__ Cs,
    _Float16* __restrict__ dta,
    int nmask, int nshift, int S, int act, int stride4)
{
  const int idx = blockIdx.x * 256 + threadIdx.x;
  float4 a = *(const float4*)&P[(size_t)idx * 4];
  for (int z = 1; z < S; z++) {
    float4 p = *(const float4*)&P[(size_t)(idx + (size_t)z * stride4) * 4];
    a.x += p.x; a.y += p.y; a.z += p.z; a.w += p.w;
  }
  if (bias) {
    float4 bv = *(const float4*)&bias[(idx * 4) & nmask];
    a.x += bv.x; a.y += bv.y; a.z += bv.z; a.w += bv.w;
  }
  if (act == 1) {
    a.x = fmaxf(a.x, 0.f); a.y = fmaxf(a.y, 0.f);
    a.z = fmaxf(a.z, 0.f); a.w = fmaxf(a.w, 0.f);
  } else if (act == 2) {
    a.x = fmaxf(a.x, 0.f) + log1pf(__expf(-fabsf(a.x)));
    a.y = fmaxf(a.y, 0.f) + log1pf(__expf(-fabsf(a.y)));
    a.z = fmaxf(a.z, 0.f) + log1pf(__expf(-fabsf(a.z)));
    a.w = fmaxf(a.w, 0.f) + log1pf(__expf(-fabsf(a.w)));
  }
  const int c0 = (idx * 4) & nmask;
  const size_t row = (size_t)(idx * 4) >> nshift;
  if (Cs) {
    store_split2(Cs, row, c0,     a.x, a.y);
    store_split2(Cs, row, c0 + 2, a.z, a.w);
  } else {
    *(float4*)&C[(size_t)idx * 4] = a;
  }
  if (dta && c0 < 32) {
    store_split2(dta, row, c0,     a.x, a.y);
    store_split2(dta, row, c0 + 2, a.z, a.w);
  }
}

// ---------------------------------------------------------------------------
// MFMA flash attention — ROUND-6 MEASURED-GOOD VERSION (56us): pre-split K/V
// staged via global_load_lds, LDS P roundtrip, 128 queries/block.
// Grid (TT/128, HB*8).
// ---------------------------------------------------------------------------
__global__ __launch_bounds__(256) void attn_mfma_k(
    const float* __restrict__ qkv,
    const _Float16* __restrict__ Kg,
    const _Float16* __restrict__ Vg,
    _Float16* __restrict__ os)
{
  __shared__ __align__(16) _Float16 Klds[AKS * 32];     // [key][32]
  __shared__ __align__(16) _Float16 Vlds[32 * AKS];     // [plane*16+d][128]
  __shared__ float Pscr[4][16 * 18];

  const int tid = threadIdx.x;
  const int lane = tid & 63;
  const int wv = tid >> 6;
  const int quad = lane >> 4;
  const int l16 = lane & 15;
  const int qh = quad & 1;
  const int bh = blockIdx.y;
  const int b = bh >> 3;
  const int h = bh & 7;
  const int qb0 = blockIdx.x * 128;
  const int wave64 = tid & 192;

  f16x8 qa[2];
#pragma unroll
  for (int u = 0; u < 2; u++) {
    const int qrow = qb0 + wv * 32 + u * 16 + l16;
    const float* qp = qkv + (size_t)(b * TT + qrow) * 384 + h * 16 + qh * 8;
    float4 x0 = *(const float4*)&qp[0];
    float4 x1 = *(const float4*)&qp[4];
    float xv[8] = {x0.x, x0.y, x0.z, x0.w, x1.x, x1.y, x1.z, x1.w};
#pragma unroll
    for (int j = 0; j < 8; j++) {
      float q = xv[j] * 0.25f;
      _Float16 hi = (_Float16)q;
      _Float16 lo = (_Float16)(q - (float)hi);
      qa[u][j] = (quad < 2) ? hi : lo;
    }
  }

  f32x4_t oacc[2];
  float lacc[2][4];
#pragma unroll
  for (int u = 0; u < 2; u++)
#pragma unroll
    for (int r = 0; r < 4; r++) { oacc[u][r] = 0.f; lacc[u][r] = 0.f; }

  float* Pw = &Pscr[wv][0];
  const _Float16* Kb = Kg + (((size_t)bh) << 10) * 32;
  const _Float16* Vb = Vg + ((size_t)bh * 32) * 1024;

  for (int ks = 0; ks < TT; ks += AKS) {
    __syncthreads();
    // stage K (8KB) + V (8KB) via global_load_lds
    {
      const _Float16* Kt = Kb + (size_t)ks * 32;
#pragma unroll
      for (int it = 0; it < 2; it++) {
        const int cb = it * 256 + tid;
        gload16(Kt + (size_t)cb * 8, &Klds[(it * 256 + wave64) * 8]);
      }
#pragma unroll
      for (int it = 0; it < 2; it++) {
        const int cb = it * 256 + tid;
        const int rowv = cb >> 4, co = cb & 15;
        gload16(Vb + (size_t)rowv * 1024 + ks + co * 8,
                &Vlds[(it * 256 + wave64) * 8]);
      }
    }
    __syncthreads();

    for (int kt = 0; kt < AKS; kt += 16) {
      const int key = kt + l16;
      const int ph = (qh + (key >> 1)) & 3;
      f16x8 kfh = *(const f16x8*)&Klds[key * 32 + ph * 8];
      f16x8 kfl = *(const f16x8*)&Klds[key * 32 + (ph ^ 2) * 8];
      const int vko = (kt + qh * 8) ^ (l16 * 8);
      f16x8 vfh = *(const f16x8*)&Vlds[l16 * 128 + vko];
      f16x8 vfl = *(const f16x8*)&Vlds[(16 + l16) * 128 + vko];

#pragma unroll
      for (int u = 0; u < 2; u++) {
        f32x4_t s;
#pragma unroll
        for (int r = 0; r < 4; r++) s[r] = 0.f;
        s = __builtin_amdgcn_mfma_f32_16x16x32_f16(qa[u], kfh, s, 0, 0, 0);
        s = __builtin_amdgcn_mfma_f32_16x16x32_f16(qa[u], kfl, s, 0, 0, 0);
        float p[4];
#pragma unroll
        for (int r = 0; r < 4; r++) {
          p[r] = __expf(s[r]);
          lacc[u][r] += p[r];
        }
        float* ps = Pw + (quad * 4) * 18 + l16;
        ps[0] = p[0]; ps[18] = p[1]; ps[36] = p[2]; ps[54] = p[3];
        __asm__ volatile("s_waitcnt lgkmcnt(0)" ::: "memory");
        const float* pr = Pw + l16 * 18 + qh * 8;
        f16x8 pa;
#pragma unroll
        for (int j = 0; j < 8; j++) {
          float pv = pr[j];
          _Float16 hi = (_Float16)pv;
          _Float16 lo = (_Float16)(pv - (float)hi);
          pa[j] = (quad < 2) ? hi : lo;
        }
        oacc[u] = __builtin_amdgcn_mfma_f32_16x16x32_f16(pa, vfh, oacc[u], 0, 0, 0);
        oacc[u] = __builtin_amdgcn_mfma_f32_16x16x32_f16(pa, vfl, oacc[u], 0, 0, 0);
        __asm__ volatile("s_waitcnt lgkmcnt(0)" ::: "memory");
      }
    }
  }

#pragma unroll
  for (int u = 0; u < 2; u++) {
#pragma unroll
    for (int r = 0; r < 4; r++) {
      float lv = lacc[u][r];
      lv += __shfl_xor(lv, 1);
      lv += __shfl_xor(lv, 2);
      lv += __shfl_xor(lv, 4);
      lv += __shfl_xor(lv, 8);
      const float inv = 1.f / lv;
      const int qrow = qb0 + wv * 32 + u * 16 + quad * 4 + r;
      const size_t m = (size_t)(b * TT + qrow);
      store_split(os, m, h * 16 + l16, oacc[u][r] * inv);
    }
  }
}

// ---------------------------------------------------------------------------
// out = LN(a + bvec) * w + bb  (fp32 out + fused split out)
// ---------------------------------------------------------------------------
__global__ __launch_bounds__(256) void add_ln_k(
    const float* __restrict__ a, const float* __restrict__ bvec,
    const float* __restrict__ w, const float* __restrict__ bb,
    float* __restrict__ out, _Float16* __restrict__ outs)
{
  const int tid = threadIdx.x;
  const int wave = tid >> 6, lane = tid & 63;
  const size_t row = (size_t)blockIdx.x * 4 + wave;
  const float* pa = a + row * 128;
  const float* pb = bvec + row * 128;
  float v0 = pa[lane] + pb[lane];
  float v1 = pa[lane + 64] + pb[lane + 64];
  float s1 = v0 + v1, s2 = v0 * v0 + v1 * v1;
#pragma unroll
  for (int off = 32; off; off >>= 1) {
    s1 += __shfl_down(s1, off);
    s2 += __shfl_down(s2, off);
  }
  s1 = __shfl(s1, 0); s2 = __shfl(s2, 0);
  const float mean = s1 * (1.f / 128.f);
  const float var = s2 * (1.f / 128.f) - mean * mean;
  const float rs = rsqrtf(var + EPSV);
  const float o0 = (v0 - mean) * rs * w[lane] + bb[lane];
  const float o1 = (v1 - mean) * rs * w[lane + 64] + bb[lane + 64];
  out[row * 128 + lane] = o0;
  out[row * 128 + lane + 64] = o1;
  store_split(outs, row, lane, o0);
  store_split(outs, row, lane + 64, o1);
}

// ---------------------------------------------------------------------------
// Depthwise causal conv (DC=4) + SiLU; 4 t-steps x 2 channels per thread.
// SPLIT-ONLY output (scans reconstruct hi+lo) — halves write traffic.
// ---------------------------------------------------------------------------
__global__ __launch_bounds__(256) void conv_silu_k(
    const float* __restrict__ xz, const float* __restrict__ cw,
    const float* __restrict__ cb, _Float16* __restrict__ outs)
{
  const int idx = blockIdx.x * 256 + threadIdx.x;   // over (MM/4)*512
  const int di = (idx & 511) * 2;
  const int tg = idx >> 9;
  const int m0 = tg * 4;
  const int t0 = m0 & (TT - 1);

  float wa[4], wb[4];
#pragma unroll
  for (int k = 0; k < 4; k++) {
    wa[k] = cw[di * 4 + k];
    wb[k] = cw[di * 4 + 4 + k];
  }
  const float b0 = cb[di], b1 = cb[di + 1];

  float2 xr[7];
#pragma unroll
  for (int j = 0; j < 7; j++) {
    if (t0 + j - 3 >= 0) {
      xr[j] = *(const float2*)&xz[(size_t)(m0 + j - 3) * 2048 + di];
    } else {
      xr[j].x = 0.f; xr[j].y = 0.f;
    }
  }

#pragma unroll
  for (int j = 0; j < 4; j++) {
    float a0 = b0, a1 = b1;
#pragma unroll
    for (int k = 0; k < 4; k++) {
      a0 += xr[j + k].x * wa[k];
      a1 += xr[j + k].y * wb[k];
    }
    const float y0 = a0 / (1.f + __expf(-a0));
    const float y1 = a1 / (1.f + __expf(-a1));
    store_split2(outs, (size_t)(m0 + j), di, y0, y1);
  }
}

// ---------------------------------------------------------------------------
// Chunked selective scan, phase A: local scan, emit P=prod(dA), S=local h.
// xi read from SPLIT buffer (hi+lo reconstruction).
// ---------------------------------------------------------------------------
__global__ __launch_bounds__(64) void scan_partial_k(
    const float* __restrict__ dt,
    const float* __restrict__ dbc,
    const _Float16* __restrict__ xis,
    const float* __restrict__ Alog,
    float* __restrict__ Pb, float* __restrict__ Sb)
{
  const int slice = blockIdx.x & 15;
  const int c = blockIdx.x >> 4;
  const int b = blockIdx.y;
  const int di = slice * 64 + threadIdx.x;

  float A[NSTATE];
#pragma unroll
  for (int n = 0; n < NSTATE; n++) A[n] = -__expf(Alog[di * NSTATE + n]);
  float h[NSTATE], P[NSTATE];
#pragma unroll
  for (int n = 0; n < NSTATE; n++) { h[n] = 0.f; P[n] = 1.f; }

  const size_t m0 = (size_t)b * TT + (size_t)c * CHUNK;
  for (int t = 0; t < CHUNK; t++) {
    const size_t m = m0 + t;
    const float dtv = dt[m * 1024 + di];
    const float xv  = load_split(xis, m, di);
    const float dtx = dtv * xv;
#pragma unroll
    for (int n = 0; n < NSTATE; n++) {
      const float Bv = dbc[m * 64 + 32 + n];
      const float dA = __expf(dtv * A[n]);
      h[n] = h[n] * dA + dtx * Bv;
      P[n] *= dA;
    }
  }
  const size_t base = (((size_t)b * NCH + c) * NSTATE) * 1024 + di;
#pragma unroll
  for (int n = 0; n < NSTATE; n++) {
    Pb[base + (size_t)n * 1024] = P[n];
    Sb[base + (size_t)n * 1024] = h[n];
  }
}

// ---------------------------------------------------------------------------
// Phase B: sequential chunk fix-up, one thread per (b, di, n).
// ---------------------------------------------------------------------------
__global__ __launch_bounds__(256) void scan_fix_k(
    float* __restrict__ Pb, const float* __restrict__ Sb)
{
  const int idx = blockIdx.x * 256 + threadIdx.x;   // over HB*16*1024
  const int di = idx & 1023;
  const int n  = (idx >> 10) & 15;
  const int b  = idx >> 14;
  float h = 0.f;
  for (int c = 0; c < NCH; c++) {
    const size_t base = (((size_t)b * NCH + c) * NSTATE + n) * 1024 + di;
    const float P = Pb[base];
    const float S = Sb[base];
    Pb[base] = h;
    h = P * h + S;
  }
}

// ---------------------------------------------------------------------------
// Phase C: re-run each chunk from h_in; y = dot(h,C) + D*x; *= silu(z).
// xi from SPLIT buffer; writes SPLIT Y.
// ---------------------------------------------------------------------------
__global__ __launch_bounds__(64) void scan_final_k(
    const float* __restrict__ dt,
    const float* __restrict__ dbc,
    const _Float16* __restrict__ xis,
    const float* __restrict__ xz,
    const float* __restrict__ Alog,
    const float* __restrict__ Dp,
    const float* __restrict__ Hin,
    _Float16* __restrict__ Y)
{
  const int slice = blockIdx.x & 15;
  const int c = blockIdx.x >> 4;
  const int b = blockIdx.y;
  const int di = slice * 64 + threadIdx.x;

  float A[NSTATE];
#pragma unroll
  for (int n = 0; n < NSTATE; n++) A[n] = -__expf(Alog[di * NSTATE + n]);
  const float Dv = Dp[di];
  float h[NSTATE];
  const size_t hbase = (((size_t)b * NCH + c) * NSTATE) * 1024 + di;
#pragma unroll
  for (int n = 0; n < NSTATE; n++) h[n] = Hin[hbase + (size_t)n * 1024];

  const size_t m0 = (size_t)b * TT + (size_t)c * CHUNK;
  for (int t = 0; t < CHUNK; t++) {
    const size_t m = m0 + t;
    const float dtv = dt[m * 1024 + di];
    const float xv  = load_split(xis, m, di);
    const float zv  = xz[m * 2048 + 1024 + di];
    const float dtx = dtv * xv;
    float y = 0.f;
#pragma unroll
    for (int n = 0; n < NSTATE; n++) {
      const float Bv = dbc[m * 64 + 32 + n];
      const float Cv = dbc[m * 64 + 48 + n];
      const float dA = __expf(dtv * A[n]);
      h[n] = h[n] * dA + dtx * Bv;
      y += h[n] * Cv;
    }
    y += Dv * xv;
    y *= zv / (1.f + __expf(-zv));
    store_split(Y, m, di, y);
  }
}

// ---------------------------------------------------------------------------
extern "C" void kernel_launch(void* const* d_in, const int* in_sizes, int n_in,
                              void* d_out, int out_size, void* d_ws, size_t ws_size,
                              hipStream_t stream)
{
  (void)in_sizes; (void)n_in; (void)out_size; (void)ws_size;
  const float* emb      = (const float*)d_in[0];
  const float* t_wqkv   = (const float*)d_in[1];
  const float* t_bqkv   = (const float*)d_in[2];
  const float* t_wo     = (const float*)d_in[3];
  const float* t_bo     = (const float*)d_in[4];
  const float* t_ln1w   = (const float*)d_in[5];
  const float* t_ln1b   = (const float*)d_in[6];
  const float* t_w1     = (const float*)d_in[7];
  const float* t_b1     = (const float*)d_in[8];
  const float* t_w2     = (const float*)d_in[9];
  const float* t_b2     = (const float*)d_in[10];
  const float* t_ln2w   = (const float*)d_in[11];
  const float* t_ln2b   = (const float*)d_in[12];
  const float* w_in     = (const float*)d_in[13];
  const float* b_in     = (const float*)d_in[14];
  const float* m_inproj = (const float*)d_in[15];
  const float* m_convw  = (const float*)d_in[16];
  const float* m_convb  = (const float*)d_in[17];
  const float* m_xproj  = (const float*)d_in[18];
  const float* m_dtw    = (const float*)d_in[19];
  const float* m_dtb    = (const float*)d_in[20];
  const float* m_Alog   = (const float*)d_in[21];
  const float* m_D      = (const float*)d_in[22];
  const float* m_outproj= (const float*)d_in[23];
  const float* w_out    = (const float*)d_in[24];
  const float* b_out    = (const float*)d_in[25];

  // Workspace: EXACTLY the round-0 footprint (MM*6208 floats, 203.4 MB).
  float* ws = (float*)d_ws;
  float* R1 = ws;                         // MM*512   x fp32 | mamba xos/xcs
  float* R2 = ws + (size_t)MM * 512;      // MM*512   wo partials + KV split | mamba xcs/xos
  float* R3 = ws + (size_t)MM * 1024;     // MM*2048  qkv | w1 split | xz | outproj partials
  float* R4 = ws + (size_t)MM * 3072;     // MM*1024  transformer weight splits | scan-Y split
  float* R5 = ws + (size_t)MM * 4096;     // MM*1024  wo/w2 out fp32 | dt fp32
  float* R6 = ws + (size_t)MM * 5120;     // MM*1024  ASP1 + w2 partials | xi-split
  float* R7 = ws + (size_t)MM * 6144;     // MM*64    dbc

  // transformer weight splits in R4 (dead once the mamba phase starts)
  _Float16* TWQKV = (_Float16*)R4;                    // 6*384  x 128
  _Float16* TWO   = TWQKV + (size_t)294912 * 2;       // 6*128  x 128
  _Float16* TW1   = TWO   + (size_t)98304 * 2;        // 6*2048 x 128
  _Float16* TW2   = TW1   + (size_t)1572864 * 2;      // 6*128  x 2048
  _Float16* TWIN  = TW2   + (size_t)1572864 * 2;      // 512    x 128  (ends at MM*440)

  _Float16* ASP1 = (_Float16*)R6;                     // M x 128 split (transformer)
  _Float16* XIS  = (_Float16*)R6;                     // M x 1024 split (mamba xi)
  _Float16* YSP  = (_Float16*)R4;                     // M x 1024 split (scan out)

  // attention K/V split buffers in R2 tail (wo partials use R2[0:MM*256))
  _Float16* KG = (_Float16*)(R2 + (size_t)MM * 256);  // 64*1024*32 halves (4MB)
  _Float16* VG = (_Float16*)(R2 + (size_t)MM * 320);  // 64*32*1024 halves (4MB)

  dim3 blk(256);
  auto split = [&](const float* src, int lda, int rows, int K, _Float16* dst) {
    hipLaunchKernelGGL(split_k, dim3(rows * (K / 32) / 256), blk, 0, stream,
                       src, lda, rows, dst);
  };
  auto gemm = [&](const _Float16* Ap, const _Float16* Wp, int wstr,
                  const float* bias, float* C, int N, int K, int act,
                  int S, float* P, _Float16* Cs, _Float16* dta, bool tn64) {
    dim3 g((N / (tn64 ? 64 : 128)) * (MM / 128), 1, S);
    if (tn64)
      hipLaunchKernelGGL(gemm_ps_t<64>, g, blk, 0, stream,
                         Ap, MM, Wp, wstr, bias, C, P, Cs, N, K, S, act);
    else
      hipLaunchKernelGGL(gemm_ps_t<128>, g, blk, 0, stream,
                         Ap, MM, Wp, wstr, bias, C, P, Cs, N, K, S, act);
    if (S > 1) {
      int stride4 = (int)((size_t)MM * N / 4);
      hipLaunchKernelGGL(reduce_k, dim3(stride4 / 256), blk, 0, stream,
                         P, bias, C, Cs, dta, N - 1, __builtin_ctz(N), S, act,
                         stride4);
    }
  };

  // ---- one-time splits, single launch (wqkv|wo|w1|w2|w_in|emb) ----
  hipLaunchKernelGGL(split6_k, dim3(568), blk, 0, stream,
      t_wqkv, 128,  2304, TWQKV,  36,
      t_wo,   128,   768, TWO,    48,
      t_w1,   128, 12288, TW1,   240,
      t_w2,  2048,   768, TW2,   432,
      w_in,   128,   512, TWIN,  440,
      emb,    128,    MM, ASP1);

  // ---- transformer stack ----
  const float* x = emb;
  for (int l = 0; l < NTT; l++) {
    // qkv: N=384 K=128, plain fp32 out -> R3
    gemm(ASP1, TWQKV + (size_t)l * 384 * 64, 2304, t_bqkv + l * 384,
         R3, 384, 128, 0, 1, nullptr, nullptr, nullptr, false);
    // K/V -> split buffers (coalesced)
    hipLaunchKernelGGL(kv_split_k, dim3(8, HB * 8), blk, 0, stream,
                       R3, KG, VG);
    // attention -> split ASP1 (wo's A)
    hipLaunchKernelGGL(attn_mfma_k, dim3(TT / 128, HB * 8), blk, 0, stream,
                       R3, KG, VG, ASP1);
    // wo: N=128 K=128, S=2, partials in R2 head
    gemm(ASP1, TWO + (size_t)l * 128 * 64, 768, t_bo + l * 128,
         R5, 128, 128, 0, 2, R2, nullptr, nullptr, true);
    hipLaunchKernelGGL(add_ln_k, dim3(MM / 4), blk, 0, stream,
                       x, R5, t_ln1w + l * 128, t_ln1b + l * 128, R1, ASP1);
    // w1: N=2048 K=128, relu, split-only output overlaid in R3 (w2's A)
    gemm(ASP1, TW1 + (size_t)l * 2048 * 64, 12288, t_b1 + l * 2048,
         R3, 2048, 128, 1, 1, nullptr, (_Float16*)R3, nullptr, false);
    // w2: N=128 K=2048, S=8, partials fill R6 (ASP1 dead here)
    gemm((_Float16*)R3, TW2 + (size_t)l * 128 * 64, 768, t_b2 + l * 128,
         R5, 128, 2048, 0, 8, R6, nullptr, nullptr, false);
    hipLaunchKernelGGL(add_ln_k, dim3(MM / 4), blk, 0, stream,
                       R1, R5, t_ln2w + l * 128, t_ln2b + l * 128, R1, ASP1);
    x = R1;
  }

  // w_in: N=512 K=128, split-only output -> R2 (mamba x)
  gemm(ASP1, TWIN, 512, b_in, R2, 512, 128, 0, 1, nullptr, (_Float16*)R2,
       nullptr, false);

  float* xcs = R2;
  float* xos = R1;
  for (int l = 0; l < NMM; l++) {
    // per-layer mamba weight splits into dead slivers of xos:
    //   inproj [256:384), xproj [384:392), dtw [392:396), DTA [396:428)
    _Float16* WIs = (_Float16*)(xos + (size_t)MM * 256);
    _Float16* WXs = (_Float16*)(xos + (size_t)MM * 384);
    _Float16* WDs = (_Float16*)(xos + (size_t)MM * 392);
    _Float16* DTA = (_Float16*)(xos + (size_t)MM * 396);
    _Float16* WOs = (_Float16*)(xos + (size_t)MM * 256);  // after scan_fix
    hipLaunchKernelGGL(split3_k, dim3(140), blk, 0, stream,
        m_inproj + (size_t)l * 2048 * 512, 512, 2048, WIs, 128,
        m_xproj  + (size_t)l * 64 * 1024, 1024,   64, WXs,   8,
        m_dtw    + (size_t)l * 1024 * 32,   32, 1024, WDs);

    // inproj: N=2048 K=512, fp32 out (conv + z) -> R3
    gemm((_Float16*)xcs, WIs, 2048, nullptr,
         R3, 2048, 512, 0, 1, nullptr, nullptr, nullptr, false);
    // conv+silu: split-only xi -> XIS (R6)
    hipLaunchKernelGGL(conv_silu_k, dim3(MM / 2), blk, 0, stream,
                       R3, m_convw + (size_t)l * 1024 * 4, m_convb + l * 1024,
                       XIS);
    // xproj: N=64 K=1024, S=4, partials xos[0:256); reduce also emits DTA
    gemm(XIS, WXs, 64, nullptr,
         R7, 64, 1024, 0, 4, xos, nullptr, DTA, true);
    // dtw: N=1024 K=32, softplus -> R5
    gemm(DTA, WDs, 1024, m_dtb + l * 1024,
         R5, 1024, 32, 2, 1, nullptr, nullptr, nullptr, false);

    float* Pb = xos;
    float* Sb = xos + (size_t)MM * 256;
    hipLaunchKernelGGL(scan_partial_k, dim3(16 * NCH, HB), dim3(64), 0, stream,
                       R5, R7, XIS, m_Alog + (size_t)l * 1024 * 16, Pb, Sb);
    hipLaunchKernelGGL(scan_fix_k, dim3(HB * NSTATE * 1024 / 256), blk, 0,
                       stream, Pb, Sb);
    // outproj weight split now (Sb dead, Pb still live for scan_final)
    split(m_outproj + (size_t)l * 512 * 1024, 1024, 512, 1024, WOs);
    // scan_final: xi from XIS (R6), Y split -> YSP (R4, transformer weights dead)
    hipLaunchKernelGGL(scan_final_k, dim3(16 * NCH, HB), dim3(64), 0, stream,
                       R5, R7, XIS, R3,
                       m_Alog + (size_t)l * 1024 * 16, m_D + l * 1024, Pb, YSP);

    // outproj: N=512 K=1024, A=YSP(R4), S=2, partials R3 (xz dead), split -> xos
    gemm(YSP, WOs, 512, nullptr,
         R5, 512, 1024, 0, 2, R3, (_Float16*)xos, nullptr, false);
    float* ts = xcs; xcs = xos; xos = ts;
  }

  // w_out: N=128 K=512, S=4, partials in R6 (dead); weight split in xos (dead)
  _Float16* WOUTs = (_Float16*)xos;
  split(w_out, 512, 128, 512, WOUTs);
  gemm((_Float16*)xcs, WOUTs, 128, b_out,
       (float*)d_out, 128, 512, 0, 4, R6, nullptr, nullptr, false);
}